// Round 10
// baseline (767.878 us; speedup 1.0000x reference)
//
#include <hip/hip_runtime.h>
#include <hip/hip_bf16.h>

#define B_ 2
#define S_ 4096
#define D_ 512
#define H_ 8
#define HD_ 64
#define FF_ 2048
#define NT_ (B_*S_)
#define EPS_ 1e-5f

typedef __attribute__((ext_vector_type(8))) short bf16x8;
typedef __attribute__((ext_vector_type(4))) float f32x4;
typedef __attribute__((ext_vector_type(4))) unsigned int u32x4;

__device__ __forceinline__ short f2bf(float f){
  __hip_bfloat16 h = __float2bfloat16(f);
  return __builtin_bit_cast(short, h);
}
__device__ __forceinline__ float bf2f(short s){
  return __bfloat162float(__builtin_bit_cast(__hip_bfloat16, s));
}
__device__ __forceinline__ unsigned pack2(float lo, float hi){
  return ((unsigned)(unsigned short)f2bf(hi) << 16) | (unsigned short)f2bf(lo);
}
__device__ __forceinline__ void load8(const float* p, float* f){
  f32x4 a = *(const f32x4*)p; f32x4 b = *(const f32x4*)(p+4);
  #pragma unroll
  for (int j=0;j<4;j++){ f[j]=a[j]; f[4+j]=b[j]; }
}
__device__ __forceinline__ void load8(const short* p, float* f){
  bf16x8 v = *(const bf16x8*)p;
  #pragma unroll
  for (int j=0;j<8;j++) f[j]=bf2f(v[j]);
}
__device__ __forceinline__ float ldval(const float* p, size_t i){ return p[i]; }
__device__ __forceinline__ float ldval(const short* p, size_t i){ return bf2f(p[i]); }
__device__ __forceinline__ void stval(float* p, size_t i, float v){ p[i]=v; }
__device__ __forceinline__ void stval(short* p, size_t i, float v){ p[i]=f2bf(v); }

#define GLL(src, dst) __builtin_amdgcn_global_load_lds( \
    (const __attribute__((address_space(1))) void*)(src), \
    (__attribute__((address_space(3))) void*)(dst), 16, 0, 0)

// ------------- transpose: W (KxN fp32) -> WT (NxK bf16) -------------
__global__ __launch_bounds__(256) void transpose_bf(const float* __restrict__ W,
                                                    short* __restrict__ WT, int K, int N){
  __shared__ float tile[32][33];
  int n0 = blockIdx.x*32, k0 = blockIdx.y*32;
  int tx = threadIdx.x, ty = threadIdx.y; // 32 x 8
  #pragma unroll
  for (int i=0;i<32;i+=8)
    tile[ty+i][tx] = W[(size_t)(k0+ty+i)*N + n0+tx];
  __syncthreads();
  #pragma unroll
  for (int i=0;i<32;i+=8)
    WT[(size_t)(n0+ty+i)*K + k0+tx] = f2bf(tile[tx][ty+i]);
}

// ------- transpose V: (B,S,H,HD) bf16 -> VT (B*H, HD, S) bf16 -------
__global__ __launch_bounds__(256) void transpose_v(const short* __restrict__ V,
                                                   short* __restrict__ VT){
  __shared__ short tile[32][33];
  int d0 = blockIdx.x*32, s0 = blockIdx.y*32, bh = blockIdx.z;
  int b = bh >> 3, h = bh & (H_-1);
  const short* Vp = V + (size_t)b*S_*D_ + (size_t)h*HD_;
  short* VTp = VT + (size_t)bh*HD_*S_;
  int tx = threadIdx.x, ty = threadIdx.y;
  #pragma unroll
  for (int i=0;i<32;i+=8)
    tile[ty+i][tx] = Vp[(size_t)(s0+ty+i)*D_ + d0+tx];   // tile[s][d]
  __syncthreads();
  #pragma unroll
  for (int i=0;i<32;i+=8)
    VTp[(size_t)(d0+ty+i)*S_ + s0+tx] = tile[tx][ty+i];
}

// ---------- LayerNorm over D=512, one wave per token, out bf16 ----------
template<typename TIn>
__global__ __launch_bounds__(256) void ln_kernel(const TIn* __restrict__ X,
                                                 const float* __restrict__ G,
                                                 const float* __restrict__ Bt,
                                                 short* __restrict__ O){
  int wid = threadIdx.x>>6, lane = threadIdx.x&63;
  int tok = blockIdx.x*4 + wid;
  const TIn* xp = X + (size_t)tok*D_;
  float f[8]; load8(xp + lane*8, f);
  float s=0.f, s2=0.f;
  #pragma unroll
  for (int j=0;j<8;j++){ s+=f[j]; s2+=f[j]*f[j]; }
  #pragma unroll
  for (int m=1;m<64;m<<=1){ s += __shfl_xor(s,m); s2 += __shfl_xor(s2,m); }
  float mu = s*(1.f/D_);
  float var = s2*(1.f/D_) - mu*mu;
  float rr = rsqrtf(var + EPS_);
  f32x4 g0 = *(const f32x4*)(G + lane*8), g1v = *(const f32x4*)(G + lane*8 + 4);
  f32x4 b0 = *(const f32x4*)(Bt + lane*8), b1v = *(const f32x4*)(Bt + lane*8 + 4);
  bf16x8 o;
  #pragma unroll
  for (int j=0;j<4;j++){
    o[j]   = f2bf((f[j]-mu)*rr*g0[j]  + b0[j]);
    o[4+j] = f2bf((f[4+j]-mu)*rr*g1v[j] + b1v[j]);
  }
  *(bf16x8*)(O + (size_t)tok*D_ + lane*8) = o;
}

// ---- GEMM: C = A(MxK,bf16) * BT(NxK,bf16)^T + bias(fp32), epilogue ----
// BK=64, global_load_lds width-16 staging, XOR-swizzled rows.
template<int EPI, typename TR, typename TO>
__global__ __launch_bounds__(256) void gemm_bt(const short* __restrict__ A,
                                               const short* __restrict__ BT,
                                               const float* __restrict__ bias,
                                               const TR* __restrict__ res,
                                               TO* __restrict__ out,
                                               int M, int N, int K){
  __shared__ __align__(16) short As[128*64];
  __shared__ __align__(16) short Bs[128*64];
  int m0 = blockIdx.y*128, n0 = blockIdx.x*128;
  int tid = threadIdx.x, lane = tid&63, wid = tid>>6;
  int wr = wid>>1, wc = wid&1;
  int r = lane&15, qh = lane>>4;
  int srow = wid*32 + (lane>>3);
  int scole = ((lane&7)*8);
  f32x4 zero = {0.f,0.f,0.f,0.f};
  f32x4 acc[4][4];
  #pragma unroll
  for (int i=0;i<4;i++)
    #pragma unroll
    for (int j=0;j<4;j++) acc[i][j] = zero;

  for (int k0=0;k0<K;k0+=64){
    __syncthreads();
    #pragma unroll
    for (int i=0;i<4;i++){
      int row = srow + i*8;
      int cole = scole ^ ((row&7)*8);
      GLL(&A [(size_t)(m0+row)*K + k0 + cole], As + (size_t)(wid*32+i*8)*64);
      GLL(&BT[(size_t)(n0+row)*K + k0 + cole], Bs + (size_t)(wid*32+i*8)*64);
    }
    __syncthreads();
    #pragma unroll
    for (int half=0; half<2; half++){
      bf16x8 a[4], b[4];
      #pragma unroll
      for (int i=0;i<4;i++){
        int ar = wr*64+i*16+r;
        a[i] = *(const bf16x8*)((const char*)As + (size_t)ar*128 + ((qh*16+half*64) ^ ((ar&7)*16)));
        int br = wc*64+i*16+r;
        b[i] = *(const bf16x8*)((const char*)Bs + (size_t)br*128 + ((qh*16+half*64) ^ ((br&7)*16)));
      }
      #pragma unroll
      for (int mi=0;mi<4;mi++)
        #pragma unroll
        for (int ni=0;ni<4;ni++)
          acc[mi][ni] = __builtin_amdgcn_mfma_f32_16x16x32_bf16(a[mi], b[ni], acc[mi][ni], 0,0,0);
    }
  }
  #pragma unroll
  for (int mi=0;mi<4;mi++){
    #pragma unroll
    for (int ni=0;ni<4;ni++){
      int col = n0 + wc*64 + ni*16 + r;
      float bs = bias[col];
      #pragma unroll
      for (int j=0;j<4;j++){
        int row = m0 + wr*64 + mi*16 + (lane>>4)*4 + j;
        float v = acc[mi][ni][j] + bs;
        if (EPI==1) v += ldval(res, (size_t)row*N + col);
        if (EPI==2) v = 0.5f*v*(1.f + erff(v*0.70710678118f));
        stval(out, (size_t)row*N + col, v);
      }
    }
  }
}

// -------- attention: block = 128 q-rows of one (b,h); 8 waves x eighth-S.
// Fused two-sweep; per-wave private K/V LDS dbuf (global_load_lds + counted
// vmcnt, XOR-swizzle), swapped-operand QK^T (lane=q-row), register-exchange P.
// q-reuse per staged byte = 128 rows -> reads ~0.78 GB (vs 1.6 GB at 64 rows).
__global__ __launch_bounds__(512, 2) void attn_kernel(const short* __restrict__ Q,
                                                      const short* __restrict__ Kt,
                                                      const short* __restrict__ VT,
                                                      float* __restrict__ attn_o,
                                                      short* __restrict__ ctx){
  __shared__ __align__(16) char smem[131072];   // 8 waves x 16KB staging; combine aliases
  __shared__ float dcomb[8][8][16];
  int wid = threadIdx.x>>6, lane = threadIdx.x&63;
  int bh = blockIdx.y, b = bh>>3, h = bh&7;
  int q0 = blockIdx.x*128;
  int koff = wid*512;                   // this wave's eighth of the keys
  int r = lane&15, qh = lane>>4;
  bool hi4 = (lane>>4)&1, hi5 = (lane>>5)&1;
  const short* Qp = Q  + (size_t)b*S_*D_ + (size_t)h*HD_;
  const short* Kp = Kt + (size_t)b*S_*D_ + (size_t)h*HD_;
  const short* Vp = VT + (size_t)bh*HD_*S_;
  float* Ap = attn_o + (size_t)bh*S_*S_;

  char* stg = smem + wid*16384;
  short* KB0 = (short*)stg;         short* KB1 = (short*)(stg+4096);
  short* VB0 = (short*)(stg+8192);  short* VB1 = (short*)(stg+12288);

  auto stageK = [&](int sc, short* buf){
    #pragma unroll
    for (int i=0;i<4;i++){
      int row = i*8 + (lane>>3);
      int col = ((lane&7)*8) ^ ((row&7)*8);
      GLL(&Kp[(size_t)(sc+row)*D_ + col], buf + i*512);
    }
  };
  auto stageV = [&](int sc, short* buf){
    #pragma unroll
    for (int i=0;i<4;i++){
      int d = i*16 + (lane>>2);
      int col = ((lane&3)*8) ^ ((d&3)*8);
      GLL(&Vp[(size_t)d*S_ + sc + col], buf + i*512);
    }
  };
  const int kc0 = (qh*16) ^ ((r&7)<<4);
  const int kc1 = (64 + qh*16) ^ ((r&7)<<4);
  const int vc  = (qh*16) ^ ((r&3)<<4);

  bf16x8 aq[8][2];
  #pragma unroll
  for (int qt=0;qt<8;qt++){
    aq[qt][0] = *(const bf16x8*)&Qp[(size_t)(q0+qt*16+r)*D_ + qh*8];
    aq[qt][1] = *(const bf16x8*)&Qp[(size_t)(q0+qt*16+r)*D_ + 32 + qh*8];
  }
  const f32x4 zero = {0.f,0.f,0.f,0.f};

  // ================= sweep 1: denominator =================
  float part[8] = {0.f,0.f,0.f,0.f,0.f,0.f,0.f,0.f};

#define S1BODY(n, NW, DOSTG) { \
  asm volatile("s_waitcnt vmcnt(" #NW ")" ::: "memory"); \
  short* kb_ = ((n)&1)? KB1 : KB0; \
  bf16x8 kf0 = *(const bf16x8*)((char*)kb_ + r*128 + kc0); \
  bf16x8 kf1 = *(const bf16x8*)((char*)kb_ + r*128 + kc1); \
  bf16x8 kf2 = *(const bf16x8*)((char*)kb_ + (16+r)*128 + kc0); \
  bf16x8 kf3 = *(const bf16x8*)((char*)kb_ + (16+r)*128 + kc1); \
  asm volatile("s_waitcnt lgkmcnt(0)" ::: "memory"); \
  if (DOSTG) stageK(koff + ((n)+2)*32, kb_); \
  _Pragma("unroll") \
  for (int qt=0;qt<8;qt++){ \
    f32x4 s0 = __builtin_amdgcn_mfma_f32_16x16x32_bf16(kf0, aq[qt][0], zero, 0,0,0); \
    s0 = __builtin_amdgcn_mfma_f32_16x16x32_bf16(kf1, aq[qt][1], s0, 0,0,0); \
    f32x4 s1 = __builtin_amdgcn_mfma_f32_16x16x32_bf16(kf2, aq[qt][0], zero, 0,0,0); \
    s1 = __builtin_amdgcn_mfma_f32_16x16x32_bf16(kf3, aq[qt][1], s1, 0,0,0); \
    _Pragma("unroll") \
    for (int j=0;j<4;j++) part[qt] += __expf(s0[j]*0.125f) + __expf(s1[j]*0.125f); \
  } \
}

  stageK(koff, KB0); stageK(koff+32, KB1);
  S1BODY(0,4,1)
  for (int k2=0;k2<6;k2++){ S1BODY(2*k2+1,4,1) S1BODY(2*k2+2,4,1) }
  S1BODY(13,4,1) S1BODY(14,4,0) S1BODY(15,0,0)
#undef S1BODY

  #pragma unroll
  for (int qt=0;qt<8;qt++){
    part[qt] += __shfl_xor(part[qt],16);
    part[qt] += __shfl_xor(part[qt],32);
  }
  if (lane < 16){
    #pragma unroll
    for (int qt=0;qt<8;qt++) dcomb[wid][qt][r] = part[qt];
  }
  __syncthreads();
  float invl[8];
  #pragma unroll
  for (int qt=0;qt<8;qt++){
    float s = 0.f;
    #pragma unroll
    for (int w=0;w<8;w++) s += dcomb[w][qt][r];
    invl[qt] = 1.f/s;
  }

  // ================= sweep 2: attn store + PV =================
  f32x4 cacc[8][4];
  #pragma unroll
  for (int qt=0;qt<8;qt++)
    #pragma unroll
    for (int n2=0;n2<4;n2++) cacc[qt][n2] = zero;

#define S2BODY(n, NW, DOSTG) { \
  asm volatile("s_waitcnt vmcnt(" #NW ")" ::: "memory"); \
  short* kb_ = ((n)&1)? KB1 : KB0; \
  short* vb_ = ((n)&1)? VB1 : VB0; \
  int sc_ = koff + (n)*32; \
  bf16x8 kf0 = *(const bf16x8*)((char*)kb_ + r*128 + kc0); \
  bf16x8 kf1 = *(const bf16x8*)((char*)kb_ + r*128 + kc1); \
  bf16x8 kf2 = *(const bf16x8*)((char*)kb_ + (16+r)*128 + kc0); \
  bf16x8 kf3 = *(const bf16x8*)((char*)kb_ + (16+r)*128 + kc1); \
  bf16x8 vf0 = *(const bf16x8*)((char*)vb_ + (r)*64    + vc); \
  bf16x8 vf1 = *(const bf16x8*)((char*)vb_ + (16+r)*64 + vc); \
  bf16x8 vf2 = *(const bf16x8*)((char*)vb_ + (32+r)*64 + vc); \
  bf16x8 vf3 = *(const bf16x8*)((char*)vb_ + (48+r)*64 + vc); \
  asm volatile("s_waitcnt lgkmcnt(0)" ::: "memory"); \
  if (DOSTG){ stageK(koff+((n)+2)*32, kb_); stageV(koff+((n)+2)*32, vb_); } \
  _Pragma("unroll") \
  for (int qt=0;qt<8;qt++){ \
    f32x4 s0 = __builtin_amdgcn_mfma_f32_16x16x32_bf16(kf0, aq[qt][0], zero, 0,0,0); \
    s0 = __builtin_amdgcn_mfma_f32_16x16x32_bf16(kf1, aq[qt][1], s0, 0,0,0); \
    f32x4 s1 = __builtin_amdgcn_mfma_f32_16x16x32_bf16(kf2, aq[qt][0], zero, 0,0,0); \
    s1 = __builtin_amdgcn_mfma_f32_16x16x32_bf16(kf3, aq[qt][1], s1, 0,0,0); \
    float e0[4], e1[4]; \
    _Pragma("unroll") \
    for (int j=0;j<4;j++){ \
      e0[j] = __expf(s0[j]*0.125f)*invl[qt]; \
      e1[j] = __expf(s1[j]*0.125f)*invl[qt]; \
    } \
    f32x4 o0 = {e0[0],e0[1],e0[2],e0[3]}; \
    f32x4 o1 = {e1[0],e1[1],e1[2],e1[3]}; \
    float* dst = &Ap[(size_t)(q0+qt*16+r)*S_ + sc_ + qh*4]; \
    *(f32x4*)dst = o0; \
    *(f32x4*)(dst+16) = o1; \
    unsigned v0 = pack2(e0[0],e0[1]), v1 = pack2(e0[2],e0[3]); \
    unsigned v2 = pack2(e1[0],e1[1]), v3 = pack2(e1[2],e1[3]); \
    unsigned u0 = __shfl_xor((int)v0,16), u1 = __shfl_xor((int)v1,16); \
    unsigned u2 = __shfl_xor((int)v2,16), u3 = __shfl_xor((int)v3,16); \
    unsigned s0c0 = hi4?u0:v0, s0c1 = hi4?u1:v1, s0c2 = hi4?v0:u0, s0c3 = hi4?v1:u1; \
    unsigned s1c0 = hi4?u2:v2, s1c1 = hi4?u3:v3, s1c2 = hi4?v2:u2, s1c3 = hi4?v3:u3; \
    unsigned w0 = hi5?s0c0:s1c0, w1 = hi5?s0c1:s1c1, w2 = hi5?s0c2:s1c2, w3 = hi5?s0c3:s1c3; \
    unsigned wp0 = __shfl_xor((int)w0,32), wp1 = __shfl_xor((int)w1,32); \
    unsigned wp2 = __shfl_xor((int)w2,32), wp3 = __shfl_xor((int)w3,32); \
    u32x4 pw; \
    pw[0] = (qh==0)?s0c0:(qh==3)?s1c0:wp0; \
    pw[1] = (qh==0)?s0c1:(qh==3)?s1c1:wp1; \
    pw[2] = (qh==0)?s0c2:(qh==3)?s1c2:wp2; \
    pw[3] = (qh==0)?s0c3:(qh==3)?s1c3:wp3; \
    bf16x8 pa = __builtin_bit_cast(bf16x8, pw); \
    cacc[qt][0] = __builtin_amdgcn_mfma_f32_16x16x32_bf16(pa, vf0, cacc[qt][0], 0,0,0); \
    cacc[qt][1] = __builtin_amdgcn_mfma_f32_16x16x32_bf16(pa, vf1, cacc[qt][1], 0,0,0); \
    cacc[qt][2] = __builtin_amdgcn_mfma_f32_16x16x32_bf16(pa, vf2, cacc[qt][2], 0,0,0); \
    cacc[qt][3] = __builtin_amdgcn_mfma_f32_16x16x32_bf16(pa, vf3, cacc[qt][3], 0,0,0); \
  } \
}

  stageK(koff, KB0); stageV(koff, VB0);
  stageK(koff+32, KB1); stageV(koff+32, VB1);
  S2BODY(0,8,1)
  for (int k2=0;k2<6;k2++){ S2BODY(2*k2+1,24,1) S2BODY(2*k2+2,24,1) }
  S2BODY(13,24,1) S2BODY(14,24,0) S2BODY(15,0,0)
#undef S2BODY

  // ---------------- 8-way PV combine (3-level LDS tree), write ctx ----------------
  __syncthreads();
  float* cmb = (float*)smem;
  // level 1: odd waves -> slot (wid>>1)
  if (wid & 1){
    float* dstp = cmb + (size_t)(wid>>1)*8192;
    #pragma unroll
    for (int qt=0;qt<8;qt++)
      #pragma unroll
      for (int n2=0;n2<4;n2++)
        #pragma unroll
        for (int j=0;j<4;j++)
          dstp[(qt*16+qh*4+j)*64 + n2*16 + r] = cacc[qt][n2][j];
  }
  __syncthreads();
  if (!(wid & 1)){
    float* srcp = cmb + (size_t)(wid>>1)*8192;
    #pragma unroll
    for (int qt=0;qt<8;qt++)
      #pragma unroll
      for (int n2=0;n2<4;n2++)
        #pragma unroll
        for (int j=0;j<4;j++)
          cacc[qt][n2][j] += srcp[(qt*16+qh*4+j)*64 + n2*16 + r];
  }
  __syncthreads();
  // level 2: waves 2,6 -> slot (wid>>2)
  if (!(wid & 1) && (wid & 2)){
    float* dstp = cmb + (size_t)(wid>>2)*8192;
    #pragma unroll
    for (int qt=0;qt<8;qt++)
      #pragma unroll
      for (int n2=0;n2<4;n2++)
        #pragma unroll
        for (int j=0;j<4;j++)
          dstp[(qt*16+qh*4+j)*64 + n2*16 + r] = cacc[qt][n2][j];
  }
  __syncthreads();
  if (!(wid & 3)){   // waves 0,4
    float* srcp = cmb + (size_t)(wid>>2)*8192;
    #pragma unroll
    for (int qt=0;qt<8;qt++)
      #pragma unroll
      for (int n2=0;n2<4;n2++)
        #pragma unroll
        for (int j=0;j<4;j++)
          cacc[qt][n2][j] += srcp[(qt*16+qh*4+j)*64 + n2*16 + r];
  }
  __syncthreads();
  // level 3: wave 4 -> slot 0
  if (wid == 4){
    #pragma unroll
    for (int qt=0;qt<8;qt++)
      #pragma unroll
      for (int n2=0;n2<4;n2++)
        #pragma unroll
        for (int j=0;j<4;j++)
          cmb[(qt*16+qh*4+j)*64 + n2*16 + r] = cacc[qt][n2][j];
  }
  __syncthreads();
  if (wid == 0){
    #pragma unroll
    for (int qt=0;qt<8;qt++)
      #pragma unroll
      for (int n2=0;n2<4;n2++)
        #pragma unroll
        for (int j=0;j<4;j++){
          float v = cacc[qt][n2][j] + cmb[(qt*16+qh*4+j)*64 + n2*16 + r];
          ctx[(size_t)(b*S_ + q0 + qt*16 + qh*4 + j)*D_ + h*HD_ + n2*16 + r] = f2bf(v);
        }
  }
}

// --------------------------------- host ---------------------------------
extern "C" void kernel_launch(void* const* d_in, const int* in_sizes, int n_in,
                              void* d_out, int out_size, void* d_ws, size_t ws_size,
                              hipStream_t stream){
  const float* x   = (const float*)d_in[0];
  const float* Wq  = (const float*)d_in[1];
  const float* bq  = (const float*)d_in[2];
  const float* Wk  = (const float*)d_in[3];
  const float* bk  = (const float*)d_in[4];
  const float* Wv  = (const float*)d_in[5];
  const float* bv  = (const float*)d_in[6];
  const float* Wo  = (const float*)d_in[7];
  const float* bo  = (const float*)d_in[8];
  const float* W1  = (const float*)d_in[9];
  const float* b1  = (const float*)d_in[10];
  const float* W2  = (const float*)d_in[11];
  const float* b2  = (const float*)d_in[12];
  const float* g1  = (const float*)d_in[13];
  const float* be1 = (const float*)d_in[14];
  const float* g2  = (const float*)d_in[15];
  const float* be2 = (const float*)d_in[16];

  char* ws = (char*)d_ws;
  const size_t KB = 1024;
  short* wqT = (short*)(ws + 0*KB);
  short* wkT = (short*)(ws + 512*KB);
  short* wvT = (short*)(ws + 1024*KB);
  short* woT = (short*)(ws + 1536*KB);
  short* w1T = (short*)(ws + 2048*KB);    // 2 MB
  short* w2T = (short*)(ws + 4096*KB);    // 2 MB
  short* hbf = (short*)(ws + 6144*KB);    // 8 MB  (LN1 out; reused for LN2 out)
  short* Qb  = (short*)(ws + 14336*KB);   // 8 MB
  short* Kb  = (short*)(ws + 22528*KB);   // 8 MB
  short* Vb  = (short*)(ws + 30720*KB);   // 8 MB
  short* VTb = (short*)(ws + 38912*KB);   // 8 MB
  short* ctx = (short*)(ws + 47104*KB);   // 8 MB
  short* f1  = (short*)(ws + 14336*KB);   // 32 MB, aliases Q/K/V/VT (dead after attn)

  float* out0 = (float*)d_out;                      // [8192,512] fp32; also holds x1
  float* attn = out0 + (size_t)NT_*D_;              // [16,4096,4096] fp32

  dim3 tb(32,8);
  transpose_bf<<<dim3(16,16),tb,0,stream>>>(Wq, wqT, 512, 512);
  transpose_bf<<<dim3(16,16),tb,0,stream>>>(Wk, wkT, 512, 512);
  transpose_bf<<<dim3(16,16),tb,0,stream>>>(Wv, wvT, 512, 512);
  transpose_bf<<<dim3(16,16),tb,0,stream>>>(Wo, woT, 512, 512);
  transpose_bf<<<dim3(64,16),tb,0,stream>>>(W1, w1T, 512, 2048);
  transpose_bf<<<dim3(16,64),tb,0,stream>>>(W2, w2T, 2048, 512);

  ln_kernel<float><<<NT_/4, 256, 0, stream>>>(x, g1, be1, hbf);

  gemm_bt<0,float,short><<<dim3(4,64),256,0,stream>>>(hbf, wqT, bq, nullptr, Qb, NT_, 512, 512);
  gemm_bt<0,float,short><<<dim3(4,64),256,0,stream>>>(hbf, wkT, bk, nullptr, Kb, NT_, 512, 512);
  gemm_bt<0,float,short><<<dim3(4,64),256,0,stream>>>(hbf, wvT, bv, nullptr, Vb, NT_, 512, 512);

  transpose_v<<<dim3(2,128,16),tb,0,stream>>>(Vb, VTb);

  attn_kernel<<<dim3(32,16), 512, 0, stream>>>(Qb, Kb, VTb, attn, ctx);

  // x1 = x + ctx@Wo + bo   -> stored fp32 in out0
  gemm_bt<1,float,float><<<dim3(4,64),256,0,stream>>>(ctx, woT, bo, x, out0, NT_, 512, 512);

  ln_kernel<float><<<NT_/4, 256, 0, stream>>>(out0, g2, be2, hbf);

  gemm_bt<2,float,short><<<dim3(16,64),256,0,stream>>>(hbf, w1T, b1, nullptr, f1, NT_, 2048, 512);

  // out = x1 + f1@W2 + b2  (in-place residual read from out0 is per-element safe)
  gemm_bt<1,float,float><<<dim3(4,64),256,0,stream>>>(f1, w2T, b2, out0, out0, NT_, 512, 2048);
}

// Round 11
// 602.066 us; speedup vs baseline: 1.2754x; 1.2754x over previous
//
#include <hip/hip_runtime.h>
#include <hip/hip_bf16.h>

#define B_ 2
#define S_ 4096
#define D_ 512
#define H_ 8
#define HD_ 64
#define FF_ 2048
#define NT_ (B_*S_)
#define EPS_ 1e-5f

typedef __attribute__((ext_vector_type(8))) short bf16x8;
typedef __attribute__((ext_vector_type(4))) float f32x4;
typedef __attribute__((ext_vector_type(4))) unsigned int u32x4;

__device__ __forceinline__ short f2bf(float f){
  __hip_bfloat16 h = __float2bfloat16(f);
  return __builtin_bit_cast(short, h);
}
__device__ __forceinline__ float bf2f(short s){
  return __bfloat162float(__builtin_bit_cast(__hip_bfloat16, s));
}
__device__ __forceinline__ unsigned pack2(float lo, float hi){
  return ((unsigned)(unsigned short)f2bf(hi) << 16) | (unsigned short)f2bf(lo);
}
__device__ __forceinline__ void load8(const float* p, float* f){
  f32x4 a = *(const f32x4*)p; f32x4 b = *(const f32x4*)(p+4);
  #pragma unroll
  for (int j=0;j<4;j++){ f[j]=a[j]; f[4+j]=b[j]; }
}
__device__ __forceinline__ void load8(const short* p, float* f){
  bf16x8 v = *(const bf16x8*)p;
  #pragma unroll
  for (int j=0;j<8;j++) f[j]=bf2f(v[j]);
}
__device__ __forceinline__ float ldval(const float* p, size_t i){ return p[i]; }
__device__ __forceinline__ float ldval(const short* p, size_t i){ return bf2f(p[i]); }
__device__ __forceinline__ void stval(float* p, size_t i, float v){ p[i]=v; }
__device__ __forceinline__ void stval(short* p, size_t i, float v){ p[i]=f2bf(v); }

#define GLL(src, dst) __builtin_amdgcn_global_load_lds( \
    (const __attribute__((address_space(1))) void*)(src), \
    (__attribute__((address_space(3))) void*)(dst), 16, 0, 0)

// ------------- transpose: W (KxN fp32) -> WT (NxK bf16) -------------
__global__ __launch_bounds__(256) void transpose_bf(const float* __restrict__ W,
                                                    short* __restrict__ WT, int K, int N){
  __shared__ float tile[32][33];
  int n0 = blockIdx.x*32, k0 = blockIdx.y*32;
  int tx = threadIdx.x, ty = threadIdx.y; // 32 x 8
  #pragma unroll
  for (int i=0;i<32;i+=8)
    tile[ty+i][tx] = W[(size_t)(k0+ty+i)*N + n0+tx];
  __syncthreads();
  #pragma unroll
  for (int i=0;i<32;i+=8)
    WT[(size_t)(n0+ty+i)*K + k0+tx] = f2bf(tile[tx][ty+i]);
}

// ------- transpose V: (B,S,H,HD) bf16 -> VT (B*H, HD, S) bf16 -------
__global__ __launch_bounds__(256) void transpose_v(const short* __restrict__ V,
                                                   short* __restrict__ VT){
  __shared__ short tile[32][33];
  int d0 = blockIdx.x*32, s0 = blockIdx.y*32, bh = blockIdx.z;
  int b = bh >> 3, h = bh & (H_-1);
  const short* Vp = V + (size_t)b*S_*D_ + (size_t)h*HD_;
  short* VTp = VT + (size_t)bh*HD_*S_;
  int tx = threadIdx.x, ty = threadIdx.y;
  #pragma unroll
  for (int i=0;i<32;i+=8)
    tile[ty+i][tx] = Vp[(size_t)(s0+ty+i)*D_ + d0+tx];   // tile[s][d]
  __syncthreads();
  #pragma unroll
  for (int i=0;i<32;i+=8)
    VTp[(size_t)(d0+ty+i)*S_ + s0+tx] = tile[tx][ty+i];
}

// ---------- LayerNorm over D=512, one wave per token, out bf16 ----------
template<typename TIn>
__global__ __launch_bounds__(256) void ln_kernel(const TIn* __restrict__ X,
                                                 const float* __restrict__ G,
                                                 const float* __restrict__ Bt,
                                                 short* __restrict__ O){
  int wid = threadIdx.x>>6, lane = threadIdx.x&63;
  int tok = blockIdx.x*4 + wid;
  const TIn* xp = X + (size_t)tok*D_;
  float f[8]; load8(xp + lane*8, f);
  float s=0.f, s2=0.f;
  #pragma unroll
  for (int j=0;j<8;j++){ s+=f[j]; s2+=f[j]*f[j]; }
  #pragma unroll
  for (int m=1;m<64;m<<=1){ s += __shfl_xor(s,m); s2 += __shfl_xor(s2,m); }
  float mu = s*(1.f/D_);
  float var = s2*(1.f/D_) - mu*mu;
  float rr = rsqrtf(var + EPS_);
  f32x4 g0 = *(const f32x4*)(G + lane*8), g1v = *(const f32x4*)(G + lane*8 + 4);
  f32x4 b0 = *(const f32x4*)(Bt + lane*8), b1v = *(const f32x4*)(Bt + lane*8 + 4);
  bf16x8 o;
  #pragma unroll
  for (int j=0;j<4;j++){
    o[j]   = f2bf((f[j]-mu)*rr*g0[j]  + b0[j]);
    o[4+j] = f2bf((f[4+j]-mu)*rr*g1v[j] + b1v[j]);
  }
  *(bf16x8*)(O + (size_t)tok*D_ + lane*8) = o;
}

// ---- GEMM: C = A(MxK,bf16) * BT(NxK,bf16)^T + bias(fp32), epilogue ----
// BK=64, global_load_lds width-16 staging, XOR-swizzled rows.
template<int EPI, typename TR, typename TO>
__global__ __launch_bounds__(256) void gemm_bt(const short* __restrict__ A,
                                               const short* __restrict__ BT,
                                               const float* __restrict__ bias,
                                               const TR* __restrict__ res,
                                               TO* __restrict__ out,
                                               int M, int N, int K){
  __shared__ __align__(16) short As[128*64];
  __shared__ __align__(16) short Bs[128*64];
  int m0 = blockIdx.y*128, n0 = blockIdx.x*128;
  int tid = threadIdx.x, lane = tid&63, wid = tid>>6;
  int wr = wid>>1, wc = wid&1;
  int r = lane&15, qh = lane>>4;
  int srow = wid*32 + (lane>>3);
  int scole = ((lane&7)*8);
  f32x4 zero = {0.f,0.f,0.f,0.f};
  f32x4 acc[4][4];
  #pragma unroll
  for (int i=0;i<4;i++)
    #pragma unroll
    for (int j=0;j<4;j++) acc[i][j] = zero;

  for (int k0=0;k0<K;k0+=64){
    __syncthreads();
    #pragma unroll
    for (int i=0;i<4;i++){
      int row = srow + i*8;
      int cole = scole ^ ((row&7)*8);
      GLL(&A [(size_t)(m0+row)*K + k0 + cole], As + (size_t)(wid*32+i*8)*64);
      GLL(&BT[(size_t)(n0+row)*K + k0 + cole], Bs + (size_t)(wid*32+i*8)*64);
    }
    __syncthreads();
    #pragma unroll
    for (int half=0; half<2; half++){
      bf16x8 a[4], b[4];
      #pragma unroll
      for (int i=0;i<4;i++){
        int ar = wr*64+i*16+r;
        a[i] = *(const bf16x8*)((const char*)As + (size_t)ar*128 + ((qh*16+half*64) ^ ((ar&7)*16)));
        int br = wc*64+i*16+r;
        b[i] = *(const bf16x8*)((const char*)Bs + (size_t)br*128 + ((qh*16+half*64) ^ ((br&7)*16)));
      }
      #pragma unroll
      for (int mi=0;mi<4;mi++)
        #pragma unroll
        for (int ni=0;ni<4;ni++)
          acc[mi][ni] = __builtin_amdgcn_mfma_f32_16x16x32_bf16(a[mi], b[ni], acc[mi][ni], 0,0,0);
    }
  }
  #pragma unroll
  for (int mi=0;mi<4;mi++){
    #pragma unroll
    for (int ni=0;ni<4;ni++){
      int col = n0 + wc*64 + ni*16 + r;
      float bs = bias[col];
      #pragma unroll
      for (int j=0;j<4;j++){
        int row = m0 + wr*64 + mi*16 + (lane>>4)*4 + j;
        float v = acc[mi][ni][j] + bs;
        if (EPI==1) v += ldval(res, (size_t)row*N + col);
        if (EPI==2) v = 0.5f*v*(1.f + erff(v*0.70710678118f));
        stval(out, (size_t)row*N + col, v);
      }
    }
  }
}

// -------- attention: block = 128 q-rows of one (b,h); 8 waves = 2 row-halves
// x 4 key-quarters. The two waves sharing a key-quarter SHARE one K/V LDS
// double-buffer (each stages half) -> each staged byte serves 128 q-rows
// (reads 1.5 GB -> 0.78 GB). Cross-wave sync: counted own-vmcnt + raw
// s_barrier (no drain), second barrier before buffer reuse (m201 pattern).
// Per-wave state identical to R8 (no spill): cacc[4][4], aq[4][2].
__global__ __launch_bounds__(512, 2) void attn_kernel(const short* __restrict__ Q,
                                                      const short* __restrict__ Kt,
                                                      const short* __restrict__ VT,
                                                      float* __restrict__ attn_o,
                                                      short* __restrict__ ctx){
  __shared__ __align__(16) char smem[65536];   // 4 quarters x 16KB (K dbuf + V dbuf)
  __shared__ float dcomb[8][4][16];
  int wid = threadIdx.x>>6, lane = threadIdx.x&63;
  int kq = wid&3, rh = wid>>2;
  int bh = blockIdx.y, b = bh>>3, h = bh&7;
  int q0 = blockIdx.x*128;
  int qbase = q0 + rh*64;               // this wave's 64 q-rows
  int koff = kq*1024;                   // this wave-pair's quarter of the keys
  int r = lane&15, qh = lane>>4;
  bool hi4 = (lane>>4)&1, hi5 = (lane>>5)&1;
  const short* Qp = Q  + (size_t)b*S_*D_ + (size_t)h*HD_;
  const short* Kp = Kt + (size_t)b*S_*D_ + (size_t)h*HD_;
  const short* Vp = VT + (size_t)bh*HD_*S_;
  float* Ap = attn_o + (size_t)bh*S_*S_;

  char* stg = smem + kq*16384;          // shared by waves rh=0 and rh=1 of quarter kq
  short* KB0 = (short*)stg;         short* KB1 = (short*)(stg+4096);
  short* VB0 = (short*)(stg+8192);  short* VB1 = (short*)(stg+12288);

  // staging split: wave rh stages rows [rh*16, rh*16+16) of the K tile (2 GLL)
  // and d-rows [rh*32, rh*32+32) of the V tile (2 GLL).
  auto stageK = [&](int sc, short* buf){
    #pragma unroll
    for (int ii=0;ii<2;ii++){
      int i = rh*2 + ii;
      int row = i*8 + (lane>>3);
      int col = ((lane&7)*8) ^ ((row&7)*8);
      GLL(&Kp[(size_t)(sc+row)*D_ + col], buf + i*512);
    }
  };
  auto stageV = [&](int sc, short* buf){
    #pragma unroll
    for (int ii=0;ii<2;ii++){
      int i = rh*2 + ii;
      int d = i*16 + (lane>>2);
      int col = ((lane&3)*8) ^ ((d&3)*8);
      GLL(&Vp[(size_t)d*S_ + sc + col], buf + i*512);
    }
  };
  const int kc0 = (qh*16) ^ ((r&7)<<4);
  const int kc1 = (64 + qh*16) ^ ((r&7)<<4);
  const int vc  = (qh*16) ^ ((r&3)<<4);

  bf16x8 aq[4][2];
  #pragma unroll
  for (int qt=0;qt<4;qt++){
    aq[qt][0] = *(const bf16x8*)&Qp[(size_t)(qbase+qt*16+r)*D_ + qh*8];
    aq[qt][1] = *(const bf16x8*)&Qp[(size_t)(qbase+qt*16+r)*D_ + 32 + qh*8];
  }
  const f32x4 zero = {0.f,0.f,0.f,0.f};

  // ================= sweep 1: denominator (K only, 2 GLL/wave/body) =================
  float part[4] = {0.f,0.f,0.f,0.f};

#define S1BODY(n, NW, DOSTG) { \
  asm volatile("s_waitcnt vmcnt(" #NW ")" ::: "memory"); \
  __builtin_amdgcn_s_barrier(); \
  short* kb_ = ((n)&1)? KB1 : KB0; \
  bf16x8 kf0 = *(const bf16x8*)((char*)kb_ + r*128 + kc0); \
  bf16x8 kf1 = *(const bf16x8*)((char*)kb_ + r*128 + kc1); \
  bf16x8 kf2 = *(const bf16x8*)((char*)kb_ + (16+r)*128 + kc0); \
  bf16x8 kf3 = *(const bf16x8*)((char*)kb_ + (16+r)*128 + kc1); \
  asm volatile("s_waitcnt lgkmcnt(0)" ::: "memory"); \
  __builtin_amdgcn_s_barrier(); \
  if (DOSTG) stageK(koff + ((n)+2)*32, kb_); \
  _Pragma("unroll") \
  for (int qt=0;qt<4;qt++){ \
    f32x4 s0 = __builtin_amdgcn_mfma_f32_16x16x32_bf16(kf0, aq[qt][0], zero, 0,0,0); \
    s0 = __builtin_amdgcn_mfma_f32_16x16x32_bf16(kf1, aq[qt][1], s0, 0,0,0); \
    f32x4 s1 = __builtin_amdgcn_mfma_f32_16x16x32_bf16(kf2, aq[qt][0], zero, 0,0,0); \
    s1 = __builtin_amdgcn_mfma_f32_16x16x32_bf16(kf3, aq[qt][1], s1, 0,0,0); \
    _Pragma("unroll") \
    for (int j=0;j<4;j++) part[qt] += __expf(s0[j]*0.125f) + __expf(s1[j]*0.125f); \
  } \
}

  stageK(koff, KB0); stageK(koff+32, KB1);
  S1BODY(0,2,1)
  for (int k2=0;k2<14;k2++){ S1BODY(2*k2+1,2,1) S1BODY(2*k2+2,2,1) }
  S1BODY(29,2,1) S1BODY(30,2,0) S1BODY(31,0,0)
#undef S1BODY

  #pragma unroll
  for (int qt=0;qt<4;qt++){
    part[qt] += __shfl_xor(part[qt],16);
    part[qt] += __shfl_xor(part[qt],32);
  }
  if (lane < 16){
    #pragma unroll
    for (int qt=0;qt<4;qt++) dcomb[wid][qt][r] = part[qt];
  }
  __syncthreads();
  float invl[4];
  #pragma unroll
  for (int qt=0;qt<4;qt++){
    float s = dcomb[rh*4+0][qt][r] + dcomb[rh*4+1][qt][r]
            + dcomb[rh*4+2][qt][r] + dcomb[rh*4+3][qt][r];
    invl[qt] = 1.f/s;
  }

  // ================= sweep 2: attn store + PV (4 GLL + 8 stores /wave/body) =================
  f32x4 cacc[4][4];
  #pragma unroll
  for (int qt=0;qt<4;qt++)
    #pragma unroll
    for (int n2=0;n2<4;n2++) cacc[qt][n2] = zero;

#define S2BODY(n, NW, DOSTG) { \
  asm volatile("s_waitcnt vmcnt(" #NW ")" ::: "memory"); \
  __builtin_amdgcn_s_barrier(); \
  short* kb_ = ((n)&1)? KB1 : KB0; \
  short* vb_ = ((n)&1)? VB1 : VB0; \
  int sc_ = koff + (n)*32; \
  bf16x8 kf0 = *(const bf16x8*)((char*)kb_ + r*128 + kc0); \
  bf16x8 kf1 = *(const bf16x8*)((char*)kb_ + r*128 + kc1); \
  bf16x8 kf2 = *(const bf16x8*)((char*)kb_ + (16+r)*128 + kc0); \
  bf16x8 kf3 = *(const bf16x8*)((char*)kb_ + (16+r)*128 + kc1); \
  bf16x8 vf0 = *(const bf16x8*)((char*)vb_ + (r)*64    + vc); \
  bf16x8 vf1 = *(const bf16x8*)((char*)vb_ + (16+r)*64 + vc); \
  bf16x8 vf2 = *(const bf16x8*)((char*)vb_ + (32+r)*64 + vc); \
  bf16x8 vf3 = *(const bf16x8*)((char*)vb_ + (48+r)*64 + vc); \
  asm volatile("s_waitcnt lgkmcnt(0)" ::: "memory"); \
  __builtin_amdgcn_s_barrier(); \
  if (DOSTG){ stageK(koff+((n)+2)*32, kb_); stageV(koff+((n)+2)*32, vb_); } \
  _Pragma("unroll") \
  for (int qt=0;qt<4;qt++){ \
    f32x4 s0 = __builtin_amdgcn_mfma_f32_16x16x32_bf16(kf0, aq[qt][0], zero, 0,0,0); \
    s0 = __builtin_amdgcn_mfma_f32_16x16x32_bf16(kf1, aq[qt][1], s0, 0,0,0); \
    f32x4 s1 = __builtin_amdgcn_mfma_f32_16x16x32_bf16(kf2, aq[qt][0], zero, 0,0,0); \
    s1 = __builtin_amdgcn_mfma_f32_16x16x32_bf16(kf3, aq[qt][1], s1, 0,0,0); \
    float e0[4], e1[4]; \
    _Pragma("unroll") \
    for (int j=0;j<4;j++){ \
      e0[j] = __expf(s0[j]*0.125f)*invl[qt]; \
      e1[j] = __expf(s1[j]*0.125f)*invl[qt]; \
    } \
    f32x4 o0 = {e0[0],e0[1],e0[2],e0[3]}; \
    f32x4 o1 = {e1[0],e1[1],e1[2],e1[3]}; \
    float* dst = &Ap[(size_t)(qbase+qt*16+r)*S_ + sc_ + qh*4]; \
    *(f32x4*)dst = o0; \
    *(f32x4*)(dst+16) = o1; \
    unsigned v0 = pack2(e0[0],e0[1]), v1 = pack2(e0[2],e0[3]); \
    unsigned v2 = pack2(e1[0],e1[1]), v3 = pack2(e1[2],e1[3]); \
    unsigned u0 = __shfl_xor((int)v0,16), u1 = __shfl_xor((int)v1,16); \
    unsigned u2 = __shfl_xor((int)v2,16), u3 = __shfl_xor((int)v3,16); \
    unsigned s0c0 = hi4?u0:v0, s0c1 = hi4?u1:v1, s0c2 = hi4?v0:u0, s0c3 = hi4?v1:u1; \
    unsigned s1c0 = hi4?u2:v2, s1c1 = hi4?u3:v3, s1c2 = hi4?v2:u2, s1c3 = hi4?v3:u3; \
    unsigned w0 = hi5?s0c0:s1c0, w1 = hi5?s0c1:s1c1, w2 = hi5?s0c2:s1c2, w3 = hi5?s0c3:s1c3; \
    unsigned wp0 = __shfl_xor((int)w0,32), wp1 = __shfl_xor((int)w1,32); \
    unsigned wp2 = __shfl_xor((int)w2,32), wp3 = __shfl_xor((int)w3,32); \
    u32x4 pw; \
    pw[0] = (qh==0)?s0c0:(qh==3)?s1c0:wp0; \
    pw[1] = (qh==0)?s0c1:(qh==3)?s1c1:wp1; \
    pw[2] = (qh==0)?s0c2:(qh==3)?s1c2:wp2; \
    pw[3] = (qh==0)?s0c3:(qh==3)?s1c3:wp3; \
    bf16x8 pa = __builtin_bit_cast(bf16x8, pw); \
    cacc[qt][0] = __builtin_amdgcn_mfma_f32_16x16x32_bf16(pa, vf0, cacc[qt][0], 0,0,0); \
    cacc[qt][1] = __builtin_amdgcn_mfma_f32_16x16x32_bf16(pa, vf1, cacc[qt][1], 0,0,0); \
    cacc[qt][2] = __builtin_amdgcn_mfma_f32_16x16x32_bf16(pa, vf2, cacc[qt][2], 0,0,0); \
    cacc[qt][3] = __builtin_amdgcn_mfma_f32_16x16x32_bf16(pa, vf3, cacc[qt][3], 0,0,0); \
  } \
}

  stageK(koff, KB0); stageV(koff, VB0);
  stageK(koff+32, KB1); stageV(koff+32, VB1);
  S2BODY(0,4,1)
  S2BODY(1,12,1)
  S2BODY(2,20,1)
  for (int k2=0;k2<13;k2++){ S2BODY(2*k2+3,20,1) S2BODY(2*k2+4,20,1) }
  S2BODY(29,20,1) S2BODY(30,20,0) S2BODY(31,16,0)
#undef S2BODY

  // ---------------- per-row-half 4-way PV combine, write ctx ----------------
  __syncthreads();
  float* cmb = (float*)smem;
  float* base = cmb + (size_t)rh*8192;   // 32KB region per row-half (2 x 4096-float slots)
  if (kq & 1){                            // kq 1,3 -> slot kq>>1
    float* dstp = base + (size_t)(kq>>1)*4096;
    #pragma unroll
    for (int qt=0;qt<4;qt++)
      #pragma unroll
      for (int n2=0;n2<4;n2++)
        #pragma unroll
        for (int j=0;j<4;j++)
          dstp[(qt*16+qh*4+j)*64 + n2*16 + r] = cacc[qt][n2][j];
  }
  __syncthreads();
  if (!(kq & 1)){                         // kq 0,2 add
    float* srcp = base + (size_t)(kq>>1)*4096;
    #pragma unroll
    for (int qt=0;qt<4;qt++)
      #pragma unroll
      for (int n2=0;n2<4;n2++)
        #pragma unroll
        for (int j=0;j<4;j++)
          cacc[qt][n2][j] += srcp[(qt*16+qh*4+j)*64 + n2*16 + r];
  }
  __syncthreads();
  if (kq == 2){
    #pragma unroll
    for (int qt=0;qt<4;qt++)
      #pragma unroll
      for (int n2=0;n2<4;n2++)
        #pragma unroll
        for (int j=0;j<4;j++)
          base[(qt*16+qh*4+j)*64 + n2*16 + r] = cacc[qt][n2][j];
  }
  __syncthreads();
  if (kq == 0){
    #pragma unroll
    for (int qt=0;qt<4;qt++)
      #pragma unroll
      for (int n2=0;n2<4;n2++)
        #pragma unroll
        for (int j=0;j<4;j++){
          float v = cacc[qt][n2][j] + base[(qt*16+qh*4+j)*64 + n2*16 + r];
          ctx[(size_t)(b*S_ + qbase + qt*16 + qh*4 + j)*D_ + h*HD_ + n2*16 + r] = f2bf(v);
        }
  }
}

// --------------------------------- host ---------------------------------
extern "C" void kernel_launch(void* const* d_in, const int* in_sizes, int n_in,
                              void* d_out, int out_size, void* d_ws, size_t ws_size,
                              hipStream_t stream){
  const float* x   = (const float*)d_in[0];
  const float* Wq  = (const float*)d_in[1];
  const float* bq  = (const float*)d_in[2];
  const float* Wk  = (const float*)d_in[3];
  const float* bk  = (const float*)d_in[4];
  const float* Wv  = (const float*)d_in[5];
  const float* bv  = (const float*)d_in[6];
  const float* Wo  = (const float*)d_in[7];
  const float* bo  = (const float*)d_in[8];
  const float* W1  = (const float*)d_in[9];
  const float* b1  = (const float*)d_in[10];
  const float* W2  = (const float*)d_in[11];
  const float* b2  = (const float*)d_in[12];
  const float* g1  = (const float*)d_in[13];
  const float* be1 = (const float*)d_in[14];
  const float* g2  = (const float*)d_in[15];
  const float* be2 = (const float*)d_in[16];

  char* ws = (char*)d_ws;
  const size_t KB = 1024;
  short* wqT = (short*)(ws + 0*KB);
  short* wkT = (short*)(ws + 512*KB);
  short* wvT = (short*)(ws + 1024*KB);
  short* woT = (short*)(ws + 1536*KB);
  short* w1T = (short*)(ws + 2048*KB);    // 2 MB
  short* w2T = (short*)(ws + 4096*KB);    // 2 MB
  short* hbf = (short*)(ws + 6144*KB);    // 8 MB  (LN1 out; reused for LN2 out)
  short* Qb  = (short*)(ws + 14336*KB);   // 8 MB
  short* Kb  = (short*)(ws + 22528*KB);   // 8 MB
  short* Vb  = (short*)(ws + 30720*KB);   // 8 MB
  short* VTb = (short*)(ws + 38912*KB);   // 8 MB
  short* ctx = (short*)(ws + 47104*KB);   // 8 MB
  short* f1  = (short*)(ws + 14336*KB);   // 32 MB, aliases Q/K/V/VT (dead after attn)

  float* out0 = (float*)d_out;                      // [8192,512] fp32; also holds x1
  float* attn = out0 + (size_t)NT_*D_;              // [16,4096,4096] fp32

  dim3 tb(32,8);
  transpose_bf<<<dim3(16,16),tb,0,stream>>>(Wq, wqT, 512, 512);
  transpose_bf<<<dim3(16,16),tb,0,stream>>>(Wk, wkT, 512, 512);
  transpose_bf<<<dim3(16,16),tb,0,stream>>>(Wv, wvT, 512, 512);
  transpose_bf<<<dim3(16,16),tb,0,stream>>>(Wo, woT, 512, 512);
  transpose_bf<<<dim3(64,16),tb,0,stream>>>(W1, w1T, 512, 2048);
  transpose_bf<<<dim3(16,64),tb,0,stream>>>(W2, w2T, 2048, 512);

  ln_kernel<float><<<NT_/4, 256, 0, stream>>>(x, g1, be1, hbf);

  gemm_bt<0,float,short><<<dim3(4,64),256,0,stream>>>(hbf, wqT, bq, nullptr, Qb, NT_, 512, 512);
  gemm_bt<0,float,short><<<dim3(4,64),256,0,stream>>>(hbf, wkT, bk, nullptr, Kb, NT_, 512, 512);
  gemm_bt<0,float,short><<<dim3(4,64),256,0,stream>>>(hbf, wvT, bv, nullptr, Vb, NT_, 512, 512);

  transpose_v<<<dim3(2,128,16),tb,0,stream>>>(Vb, VTb);

  attn_kernel<<<dim3(32,16), 512, 0, stream>>>(Qb, Kb, VTb, attn, ctx);

  // x1 = x + ctx@Wo + bo   -> stored fp32 in out0
  gemm_bt<1,float,float><<<dim3(4,64),256,0,stream>>>(ctx, woT, bo, x, out0, NT_, 512, 512);

  ln_kernel<float><<<NT_/4, 256, 0, stream>>>(out0, g2, be2, hbf);

  gemm_bt<2,float,short><<<dim3(16,64),256,0,stream>>>(hbf, w1T, b1, nullptr, f1, NT_, 2048, 512);

  // out = x1 + f1@W2 + b2  (in-place residual read from out0 is per-element safe)
  gemm_bt<1,float,float><<<dim3(4,64),256,0,stream>>>(f1, w2T, b2, out0, out0, NT_, 512, 2048);
}

// Round 12
// 560.179 us; speedup vs baseline: 1.3708x; 1.0748x over previous
//
#include <hip/hip_runtime.h>
#include <hip/hip_bf16.h>

#define B_ 2
#define S_ 4096
#define D_ 512
#define H_ 8
#define HD_ 64
#define FF_ 2048
#define NT_ (B_*S_)
#define EPS_ 1e-5f

typedef __attribute__((ext_vector_type(8))) short bf16x8;
typedef __attribute__((ext_vector_type(4))) float f32x4;
typedef __attribute__((ext_vector_type(4))) unsigned int u32x4;

__device__ __forceinline__ short f2bf(float f){
  __hip_bfloat16 h = __float2bfloat16(f);
  return __builtin_bit_cast(short, h);
}
__device__ __forceinline__ float bf2f(short s){
  return __bfloat162float(__builtin_bit_cast(__hip_bfloat16, s));
}
__device__ __forceinline__ unsigned pack2(float lo, float hi){
  return ((unsigned)(unsigned short)f2bf(hi) << 16) | (unsigned short)f2bf(lo);
}
__device__ __forceinline__ void load8(const float* p, float* f){
  f32x4 a = *(const f32x4*)p; f32x4 b = *(const f32x4*)(p+4);
  #pragma unroll
  for (int j=0;j<4;j++){ f[j]=a[j]; f[4+j]=b[j]; }
}
__device__ __forceinline__ void load8(const short* p, float* f){
  bf16x8 v = *(const bf16x8*)p;
  #pragma unroll
  for (int j=0;j<8;j++) f[j]=bf2f(v[j]);
}
__device__ __forceinline__ float ldval(const float* p, size_t i){ return p[i]; }
__device__ __forceinline__ float ldval(const short* p, size_t i){ return bf2f(p[i]); }
__device__ __forceinline__ void stval(float* p, size_t i, float v){ p[i]=v; }
__device__ __forceinline__ void stval(short* p, size_t i, float v){ p[i]=f2bf(v); }

#define GLL(src, dst) __builtin_amdgcn_global_load_lds( \
    (const __attribute__((address_space(1))) void*)(src), \
    (__attribute__((address_space(3))) void*)(dst), 16, 0, 0)

// ------------- transpose: W (KxN fp32) -> WT (NxK bf16) -------------
__global__ __launch_bounds__(256) void transpose_bf(const float* __restrict__ W,
                                                    short* __restrict__ WT, int K, int N){
  __shared__ float tile[32][33];
  int n0 = blockIdx.x*32, k0 = blockIdx.y*32;
  int tx = threadIdx.x, ty = threadIdx.y; // 32 x 8
  #pragma unroll
  for (int i=0;i<32;i+=8)
    tile[ty+i][tx] = W[(size_t)(k0+ty+i)*N + n0+tx];
  __syncthreads();
  #pragma unroll
  for (int i=0;i<32;i+=8)
    WT[(size_t)(n0+ty+i)*K + k0+tx] = f2bf(tile[tx][ty+i]);
}

// ------- transpose V: (B,S,H,HD) bf16 -> VT (B*H, HD, S) bf16 -------
__global__ __launch_bounds__(256) void transpose_v(const short* __restrict__ V,
                                                   short* __restrict__ VT){
  __shared__ short tile[32][33];
  int d0 = blockIdx.x*32, s0 = blockIdx.y*32, bh = blockIdx.z;
  int b = bh >> 3, h = bh & (H_-1);
  const short* Vp = V + (size_t)b*S_*D_ + (size_t)h*HD_;
  short* VTp = VT + (size_t)bh*HD_*S_;
  int tx = threadIdx.x, ty = threadIdx.y;
  #pragma unroll
  for (int i=0;i<32;i+=8)
    tile[ty+i][tx] = Vp[(size_t)(s0+ty+i)*D_ + d0+tx];   // tile[s][d]
  __syncthreads();
  #pragma unroll
  for (int i=0;i<32;i+=8)
    VTp[(size_t)(d0+ty+i)*S_ + s0+tx] = tile[tx][ty+i];
}

// ---------- LayerNorm over D=512, one wave per token, out bf16 ----------
template<typename TIn>
__global__ __launch_bounds__(256) void ln_kernel(const TIn* __restrict__ X,
                                                 const float* __restrict__ G,
                                                 const float* __restrict__ Bt,
                                                 short* __restrict__ O){
  int wid = threadIdx.x>>6, lane = threadIdx.x&63;
  int tok = blockIdx.x*4 + wid;
  const TIn* xp = X + (size_t)tok*D_;
  float f[8]; load8(xp + lane*8, f);
  float s=0.f, s2=0.f;
  #pragma unroll
  for (int j=0;j<8;j++){ s+=f[j]; s2+=f[j]*f[j]; }
  #pragma unroll
  for (int m=1;m<64;m<<=1){ s += __shfl_xor(s,m); s2 += __shfl_xor(s2,m); }
  float mu = s*(1.f/D_);
  float var = s2*(1.f/D_) - mu*mu;
  float rr = rsqrtf(var + EPS_);
  f32x4 g0 = *(const f32x4*)(G + lane*8), g1v = *(const f32x4*)(G + lane*8 + 4);
  f32x4 b0 = *(const f32x4*)(Bt + lane*8), b1v = *(const f32x4*)(Bt + lane*8 + 4);
  bf16x8 o;
  #pragma unroll
  for (int j=0;j<4;j++){
    o[j]   = f2bf((f[j]-mu)*rr*g0[j]  + b0[j]);
    o[4+j] = f2bf((f[4+j]-mu)*rr*g1v[j] + b1v[j]);
  }
  *(bf16x8*)(O + (size_t)tok*D_ + lane*8) = o;
}

// ---- GEMM 128x128: C = A(MxK,bf16) * BT(NxK,bf16)^T + bias(fp32), epilogue ----
// EPI: 0 = bias only; 1 = bias + residual; 2 = bias + exact GELU
template<int EPI, typename TR, typename TO>
__global__ __launch_bounds__(256) void gemm_bt(const short* __restrict__ A,
                                               const short* __restrict__ BT,
                                               const float* __restrict__ bias,
                                               const TR* __restrict__ res,
                                               TO* __restrict__ out,
                                               int M, int N, int K){
  __shared__ short As[128][40];
  __shared__ short Bs[128][40];
  int m0 = blockIdx.y*128, n0 = blockIdx.x*128;
  int tid = threadIdx.x, lane = tid&63, wid = tid>>6;
  int wr = wid>>1, wc = wid&1;
  int r = lane&15, kk = (lane>>4)*8;
  int arow = tid>>2, acol = (tid&3)*8;
  f32x4 zero = {0.f,0.f,0.f,0.f};
  f32x4 acc[4][4];
  #pragma unroll
  for (int i=0;i<4;i++)
    #pragma unroll
    for (int j=0;j<4;j++) acc[i][j] = zero;

  for (int k0=0;k0<K;k0+=32){
    __syncthreads();
    *(bf16x8*)&As[arow][acol]    = *(const bf16x8*)&A [(size_t)(m0+arow)*K    + k0+acol];
    *(bf16x8*)&As[arow+64][acol] = *(const bf16x8*)&A [(size_t)(m0+arow+64)*K + k0+acol];
    *(bf16x8*)&Bs[arow][acol]    = *(const bf16x8*)&BT[(size_t)(n0+arow)*K    + k0+acol];
    *(bf16x8*)&Bs[arow+64][acol] = *(const bf16x8*)&BT[(size_t)(n0+arow+64)*K + k0+acol];
    __syncthreads();
    bf16x8 a[4], b[4];
    #pragma unroll
    for (int i=0;i<4;i++) a[i] = *(const bf16x8*)&As[wr*64+i*16+r][kk];
    #pragma unroll
    for (int i=0;i<4;i++) b[i] = *(const bf16x8*)&Bs[wc*64+i*16+r][kk];
    #pragma unroll
    for (int mi=0;mi<4;mi++)
      #pragma unroll
      for (int ni=0;ni<4;ni++)
        acc[mi][ni] = __builtin_amdgcn_mfma_f32_16x16x32_bf16(a[mi], b[ni], acc[mi][ni], 0,0,0);
  }
  #pragma unroll
  for (int mi=0;mi<4;mi++){
    #pragma unroll
    for (int ni=0;ni<4;ni++){
      int col = n0 + wc*64 + ni*16 + r;
      float bs = bias[col];
      #pragma unroll
      for (int j=0;j<4;j++){
        int row = m0 + wr*64 + mi*16 + (lane>>4)*4 + j;
        float v = acc[mi][ni][j] + bs;
        if (EPI==1) v += ldval(res, (size_t)row*N + col);
        if (EPI==2) v = 0.5f*v*(1.f + erff(v*0.70710678118f));
        stval(out, (size_t)row*N + col, v);
      }
    }
  }
}

// ---- GEMM 128x64 tile: for N=512-class GEMMs (grid 512 blocks -> 2+/CU) ----
// Same math/accumulation order as gemm_bt; smaller N-tile, acc[4][2], low VGPR.
template<int EPI, typename TR, typename TO>
__global__ __launch_bounds__(256) void gemm_bt64(const short* __restrict__ A,
                                                 const short* __restrict__ BT,
                                                 const float* __restrict__ bias,
                                                 const TR* __restrict__ res,
                                                 TO* __restrict__ out,
                                                 int M, int N, int K){
  __shared__ short As[128][40];
  __shared__ short Bs[64][40];
  int m0 = blockIdx.y*128, n0 = blockIdx.x*64;
  int tid = threadIdx.x, lane = tid&63, wid = tid>>6;
  int wr = wid>>1, wc = wid&1;
  int r = lane&15, kk = (lane>>4)*8;
  int arow = tid>>2, acol = (tid&3)*8;
  f32x4 zero = {0.f,0.f,0.f,0.f};
  f32x4 acc[4][2];
  #pragma unroll
  for (int i=0;i<4;i++){ acc[i][0] = zero; acc[i][1] = zero; }

  for (int k0=0;k0<K;k0+=32){
    __syncthreads();
    *(bf16x8*)&As[arow][acol]    = *(const bf16x8*)&A [(size_t)(m0+arow)*K    + k0+acol];
    *(bf16x8*)&As[arow+64][acol] = *(const bf16x8*)&A [(size_t)(m0+arow+64)*K + k0+acol];
    *(bf16x8*)&Bs[arow][acol]    = *(const bf16x8*)&BT[(size_t)(n0+arow)*K    + k0+acol];
    __syncthreads();
    bf16x8 a[4], b[2];
    #pragma unroll
    for (int i=0;i<4;i++) a[i] = *(const bf16x8*)&As[wr*64+i*16+r][kk];
    #pragma unroll
    for (int j=0;j<2;j++) b[j] = *(const bf16x8*)&Bs[wc*32+j*16+r][kk];
    #pragma unroll
    for (int mi=0;mi<4;mi++)
      #pragma unroll
      for (int nj=0;nj<2;nj++)
        acc[mi][nj] = __builtin_amdgcn_mfma_f32_16x16x32_bf16(a[mi], b[nj], acc[mi][nj], 0,0,0);
  }
  #pragma unroll
  for (int mi=0;mi<4;mi++){
    #pragma unroll
    for (int nj=0;nj<2;nj++){
      int col = n0 + wc*32 + nj*16 + r;
      float bs = bias[col];
      #pragma unroll
      for (int j=0;j<4;j++){
        int row = m0 + wr*64 + mi*16 + (lane>>4)*4 + j;
        float v = acc[mi][nj][j] + bs;
        if (EPI==1) v += ldval(res, (size_t)row*N + col);
        if (EPI==2) v = 0.5f*v*(1.f + erff(v*0.70710678118f));
        stval(out, (size_t)row*N + col, v);
      }
    }
  }
}

// -------- attention (R8-proven): block = 64 q-rows of one (b,h); 4 waves x
// quarter-S. Swapped-operand QK^T (lane = q-row). K/V async-staged to per-wave
// LDS dbuf via global_load_lds + counted vmcnt; XOR-swizzled layout.
__global__ __launch_bounds__(256, 2) void attn_kernel(const short* __restrict__ Q,
                                                      const short* __restrict__ Kt,
                                                      const short* __restrict__ VT,
                                                      float* __restrict__ attn_o,
                                                      short* __restrict__ ctx){
  __shared__ __align__(16) char smem[65536];   // 4 waves x 16KB staging; combine aliases
  __shared__ float dcomb[4][4][16];
  int wid = threadIdx.x>>6, lane = threadIdx.x&63;
  int bh = blockIdx.y, b = bh>>3, h = bh&7;
  int q0 = blockIdx.x*64;
  int koff = wid*1024;                  // this wave's quarter of the keys
  int r = lane&15, qh = lane>>4;
  bool hi4 = (lane>>4)&1, hi5 = (lane>>5)&1;
  const short* Qp = Q  + (size_t)b*S_*D_ + (size_t)h*HD_;
  const short* Kp = Kt + (size_t)b*S_*D_ + (size_t)h*HD_;
  const short* Vp = VT + (size_t)bh*HD_*S_;
  float* Ap = attn_o + (size_t)bh*S_*S_;

  char* stg = smem + wid*16384;
  short* KB0 = (short*)stg;         short* KB1 = (short*)(stg+4096);
  short* VB0 = (short*)(stg+8192);  short* VB1 = (short*)(stg+12288);

  auto stageK = [&](int sc, short* buf){
    #pragma unroll
    for (int i=0;i<4;i++){
      int row = i*8 + (lane>>3);
      int col = ((lane&7)*8) ^ ((row&7)*8);
      GLL(&Kp[(size_t)(sc+row)*D_ + col], buf + i*512);
    }
  };
  auto stageV = [&](int sc, short* buf){
    #pragma unroll
    for (int i=0;i<4;i++){
      int d = i*16 + (lane>>2);
      int col = ((lane&3)*8) ^ ((d&3)*8);
      GLL(&Vp[(size_t)d*S_ + sc + col], buf + i*512);
    }
  };
  const int kc0 = (qh*16) ^ ((r&7)<<4);
  const int kc1 = (64 + qh*16) ^ ((r&7)<<4);
  const int vc  = (qh*16) ^ ((r&3)<<4);

  bf16x8 aq[4][2];
  #pragma unroll
  for (int qt=0;qt<4;qt++){
    aq[qt][0] = *(const bf16x8*)&Qp[(size_t)(q0+qt*16+r)*D_ + qh*8];
    aq[qt][1] = *(const bf16x8*)&Qp[(size_t)(q0+qt*16+r)*D_ + 32 + qh*8];
  }
  const f32x4 zero = {0.f,0.f,0.f,0.f};

  // ================= sweep 1: denominator =================
  float part[4] = {0.f,0.f,0.f,0.f};

#define S1BODY(n, NW, DOSTG) { \
  asm volatile("s_waitcnt vmcnt(" #NW ")" ::: "memory"); \
  short* kb_ = ((n)&1)? KB1 : KB0; \
  bf16x8 kf0 = *(const bf16x8*)((char*)kb_ + r*128 + kc0); \
  bf16x8 kf1 = *(const bf16x8*)((char*)kb_ + r*128 + kc1); \
  bf16x8 kf2 = *(const bf16x8*)((char*)kb_ + (16+r)*128 + kc0); \
  bf16x8 kf3 = *(const bf16x8*)((char*)kb_ + (16+r)*128 + kc1); \
  asm volatile("s_waitcnt lgkmcnt(0)" ::: "memory"); \
  if (DOSTG) stageK(koff + ((n)+2)*32, kb_); \
  _Pragma("unroll") \
  for (int qt=0;qt<4;qt++){ \
    f32x4 s0 = __builtin_amdgcn_mfma_f32_16x16x32_bf16(kf0, aq[qt][0], zero, 0,0,0); \
    s0 = __builtin_amdgcn_mfma_f32_16x16x32_bf16(kf1, aq[qt][1], s0, 0,0,0); \
    f32x4 s1 = __builtin_amdgcn_mfma_f32_16x16x32_bf16(kf2, aq[qt][0], zero, 0,0,0); \
    s1 = __builtin_amdgcn_mfma_f32_16x16x32_bf16(kf3, aq[qt][1], s1, 0,0,0); \
    _Pragma("unroll") \
    for (int j=0;j<4;j++) part[qt] += __expf(s0[j]*0.125f) + __expf(s1[j]*0.125f); \
  } \
}

  stageK(koff, KB0); stageK(koff+32, KB1);
  S1BODY(0,4,1)
  for (int k2=0;k2<14;k2++){ S1BODY(2*k2+1,4,1) S1BODY(2*k2+2,4,1) }
  S1BODY(29,4,1) S1BODY(30,4,0) S1BODY(31,0,0)
#undef S1BODY

  #pragma unroll
  for (int qt=0;qt<4;qt++){
    part[qt] += __shfl_xor(part[qt],16);
    part[qt] += __shfl_xor(part[qt],32);
  }
  if (lane < 16){
    #pragma unroll
    for (int qt=0;qt<4;qt++) dcomb[wid][qt][r] = part[qt];
  }
  __syncthreads();
  float invl[4];
  #pragma unroll
  for (int qt=0;qt<4;qt++)
    invl[qt] = 1.f/(dcomb[0][qt][r]+dcomb[1][qt][r]+dcomb[2][qt][r]+dcomb[3][qt][r]);

  // ================= sweep 2: attn store + PV =================
  f32x4 cacc[4][4];
  #pragma unroll
  for (int qt=0;qt<4;qt++)
    #pragma unroll
    for (int n2=0;n2<4;n2++) cacc[qt][n2] = zero;

#define S2BODY(n, NW, DOSTG) { \
  asm volatile("s_waitcnt vmcnt(" #NW ")" ::: "memory"); \
  short* kb_ = ((n)&1)? KB1 : KB0; \
  short* vb_ = ((n)&1)? VB1 : VB0; \
  int sc_ = koff + (n)*32; \
  bf16x8 kf0 = *(const bf16x8*)((char*)kb_ + r*128 + kc0); \
  bf16x8 kf1 = *(const bf16x8*)((char*)kb_ + r*128 + kc1); \
  bf16x8 kf2 = *(const bf16x8*)((char*)kb_ + (16+r)*128 + kc0); \
  bf16x8 kf3 = *(const bf16x8*)((char*)kb_ + (16+r)*128 + kc1); \
  bf16x8 vf0 = *(const bf16x8*)((char*)vb_ + (r)*64    + vc); \
  bf16x8 vf1 = *(const bf16x8*)((char*)vb_ + (16+r)*64 + vc); \
  bf16x8 vf2 = *(const bf16x8*)((char*)vb_ + (32+r)*64 + vc); \
  bf16x8 vf3 = *(const bf16x8*)((char*)vb_ + (48+r)*64 + vc); \
  asm volatile("s_waitcnt lgkmcnt(0)" ::: "memory"); \
  if (DOSTG){ stageK(koff+((n)+2)*32, kb_); stageV(koff+((n)+2)*32, vb_); } \
  _Pragma("unroll") \
  for (int qt=0;qt<4;qt++){ \
    f32x4 s0 = __builtin_amdgcn_mfma_f32_16x16x32_bf16(kf0, aq[qt][0], zero, 0,0,0); \
    s0 = __builtin_amdgcn_mfma_f32_16x16x32_bf16(kf1, aq[qt][1], s0, 0,0,0); \
    f32x4 s1 = __builtin_amdgcn_mfma_f32_16x16x32_bf16(kf2, aq[qt][0], zero, 0,0,0); \
    s1 = __builtin_amdgcn_mfma_f32_16x16x32_bf16(kf3, aq[qt][1], s1, 0,0,0); \
    float e0[4], e1[4]; \
    _Pragma("unroll") \
    for (int j=0;j<4;j++){ \
      e0[j] = __expf(s0[j]*0.125f)*invl[qt]; \
      e1[j] = __expf(s1[j]*0.125f)*invl[qt]; \
    } \
    f32x4 o0 = {e0[0],e0[1],e0[2],e0[3]}; \
    f32x4 o1 = {e1[0],e1[1],e1[2],e1[3]}; \
    float* dst = &Ap[(size_t)(q0+qt*16+r)*S_ + sc_ + qh*4]; \
    *(f32x4*)dst = o0; \
    *(f32x4*)(dst+16) = o1; \
    unsigned v0 = pack2(e0[0],e0[1]), v1 = pack2(e0[2],e0[3]); \
    unsigned v2 = pack2(e1[0],e1[1]), v3 = pack2(e1[2],e1[3]); \
    unsigned u0 = __shfl_xor((int)v0,16), u1 = __shfl_xor((int)v1,16); \
    unsigned u2 = __shfl_xor((int)v2,16), u3 = __shfl_xor((int)v3,16); \
    unsigned s0c0 = hi4?u0:v0, s0c1 = hi4?u1:v1, s0c2 = hi4?v0:u0, s0c3 = hi4?v1:u1; \
    unsigned s1c0 = hi4?u2:v2, s1c1 = hi4?u3:v3, s1c2 = hi4?v2:u2, s1c3 = hi4?v3:u3; \
    unsigned w0 = hi5?s0c0:s1c0, w1 = hi5?s0c1:s1c1, w2 = hi5?s0c2:s1c2, w3 = hi5?s0c3:s1c3; \
    unsigned wp0 = __shfl_xor((int)w0,32), wp1 = __shfl_xor((int)w1,32); \
    unsigned wp2 = __shfl_xor((int)w2,32), wp3 = __shfl_xor((int)w3,32); \
    u32x4 pw; \
    pw[0] = (qh==0)?s0c0:(qh==3)?s1c0:wp0; \
    pw[1] = (qh==0)?s0c1:(qh==3)?s1c1:wp1; \
    pw[2] = (qh==0)?s0c2:(qh==3)?s1c2:wp2; \
    pw[3] = (qh==0)?s0c3:(qh==3)?s1c3:wp3; \
    bf16x8 pa = __builtin_bit_cast(bf16x8, pw); \
    cacc[qt][0] = __builtin_amdgcn_mfma_f32_16x16x32_bf16(pa, vf0, cacc[qt][0], 0,0,0); \
    cacc[qt][1] = __builtin_amdgcn_mfma_f32_16x16x32_bf16(pa, vf1, cacc[qt][1], 0,0,0); \
    cacc[qt][2] = __builtin_amdgcn_mfma_f32_16x16x32_bf16(pa, vf2, cacc[qt][2], 0,0,0); \
    cacc[qt][3] = __builtin_amdgcn_mfma_f32_16x16x32_bf16(pa, vf3, cacc[qt][3], 0,0,0); \
  } \
}

  stageK(koff, KB0); stageV(koff, VB0);
  stageK(koff+32, KB1); stageV(koff+32, VB1);
  S2BODY(0,8,1)
  for (int k2=0;k2<14;k2++){ S2BODY(2*k2+1,16,1) S2BODY(2*k2+2,16,1) }
  S2BODY(29,16,1) S2BODY(30,16,0) S2BODY(31,8,0)
#undef S2BODY

  // ---------------- 4-way PV combine, write ctx ----------------
  __syncthreads();
  float* cmb = (float*)smem;
  if (wid & 1){
    float* dstp = cmb + (wid>>1)*4096;
    #pragma unroll
    for (int qt=0;qt<4;qt++)
      #pragma unroll
      for (int n2=0;n2<4;n2++)
        #pragma unroll
        for (int j=0;j<4;j++)
          dstp[(qt*16+qh*4+j)*64 + n2*16 + r] = cacc[qt][n2][j];
  }
  __syncthreads();
  if (!(wid & 1)){
    float* srcp = cmb + (wid>>1)*4096;
    #pragma unroll
    for (int qt=0;qt<4;qt++)
      #pragma unroll
      for (int n2=0;n2<4;n2++)
        #pragma unroll
        for (int j=0;j<4;j++)
          cacc[qt][n2][j] += srcp[(qt*16+qh*4+j)*64 + n2*16 + r];
  }
  __syncthreads();
  if (wid == 2){
    #pragma unroll
    for (int qt=0;qt<4;qt++)
      #pragma unroll
      for (int n2=0;n2<4;n2++)
        #pragma unroll
        for (int j=0;j<4;j++)
          cmb[(qt*16+qh*4+j)*64 + n2*16 + r] = cacc[qt][n2][j];
  }
  __syncthreads();
  if (wid == 0){
    #pragma unroll
    for (int qt=0;qt<4;qt++)
      #pragma unroll
      for (int n2=0;n2<4;n2++)
        #pragma unroll
        for (int j=0;j<4;j++){
          float v = cacc[qt][n2][j] + cmb[(qt*16+qh*4+j)*64 + n2*16 + r];
          ctx[(size_t)(b*S_ + q0 + qt*16 + qh*4 + j)*D_ + h*HD_ + n2*16 + r] = f2bf(v);
        }
  }
}

// --------------------------------- host ---------------------------------
extern "C" void kernel_launch(void* const* d_in, const int* in_sizes, int n_in,
                              void* d_out, int out_size, void* d_ws, size_t ws_size,
                              hipStream_t stream){
  const float* x   = (const float*)d_in[0];
  const float* Wq  = (const float*)d_in[1];
  const float* bq  = (const float*)d_in[2];
  const float* Wk  = (const float*)d_in[3];
  const float* bk  = (const float*)d_in[4];
  const float* Wv  = (const float*)d_in[5];
  const float* bv  = (const float*)d_in[6];
  const float* Wo  = (const float*)d_in[7];
  const float* bo  = (const float*)d_in[8];
  const float* W1  = (const float*)d_in[9];
  const float* b1  = (const float*)d_in[10];
  const float* W2  = (const float*)d_in[11];
  const float* b2  = (const float*)d_in[12];
  const float* g1  = (const float*)d_in[13];
  const float* be1 = (const float*)d_in[14];
  const float* g2  = (const float*)d_in[15];
  const float* be2 = (const float*)d_in[16];

  char* ws = (char*)d_ws;
  const size_t KB = 1024;
  short* wqT = (short*)(ws + 0*KB);
  short* wkT = (short*)(ws + 512*KB);
  short* wvT = (short*)(ws + 1024*KB);
  short* woT = (short*)(ws + 1536*KB);
  short* w1T = (short*)(ws + 2048*KB);    // 2 MB
  short* w2T = (short*)(ws + 4096*KB);    // 2 MB
  short* hbf = (short*)(ws + 6144*KB);    // 8 MB  (LN1 out; reused for LN2 out)
  short* Qb  = (short*)(ws + 14336*KB);   // 8 MB
  short* Kb  = (short*)(ws + 22528*KB);   // 8 MB
  short* Vb  = (short*)(ws + 30720*KB);   // 8 MB
  short* VTb = (short*)(ws + 38912*KB);   // 8 MB
  short* ctx = (short*)(ws + 47104*KB);   // 8 MB
  short* f1  = (short*)(ws + 14336*KB);   // 32 MB, aliases Q/K/V/VT (dead after attn)

  float* out0 = (float*)d_out;                      // [8192,512] fp32; also holds x1
  float* attn = out0 + (size_t)NT_*D_;              // [16,4096,4096] fp32

  dim3 tb(32,8);
  transpose_bf<<<dim3(16,16),tb,0,stream>>>(Wq, wqT, 512, 512);
  transpose_bf<<<dim3(16,16),tb,0,stream>>>(Wk, wkT, 512, 512);
  transpose_bf<<<dim3(16,16),tb,0,stream>>>(Wv, wvT, 512, 512);
  transpose_bf<<<dim3(16,16),tb,0,stream>>>(Wo, woT, 512, 512);
  transpose_bf<<<dim3(64,16),tb,0,stream>>>(W1, w1T, 512, 2048);
  transpose_bf<<<dim3(16,64),tb,0,stream>>>(W2, w2T, 2048, 512);

  ln_kernel<float><<<NT_/4, 256, 0, stream>>>(x, g1, be1, hbf);

  gemm_bt64<0,float,short><<<dim3(8,64),256,0,stream>>>(hbf, wqT, bq, nullptr, Qb, NT_, 512, 512);
  gemm_bt64<0,float,short><<<dim3(8,64),256,0,stream>>>(hbf, wkT, bk, nullptr, Kb, NT_, 512, 512);
  gemm_bt64<0,float,short><<<dim3(8,64),256,0,stream>>>(hbf, wvT, bv, nullptr, Vb, NT_, 512, 512);

  transpose_v<<<dim3(2,128,16),tb,0,stream>>>(Vb, VTb);

  attn_kernel<<<dim3(64,16), 256, 0, stream>>>(Qb, Kb, VTb, attn, ctx);

  // x1 = x + ctx@Wo + bo   -> stored fp32 in out0
  gemm_bt64<1,float,float><<<dim3(8,64),256,0,stream>>>(ctx, woT, bo, x, out0, NT_, 512, 512);

  ln_kernel<float><<<NT_/4, 256, 0, stream>>>(out0, g2, be2, hbf);

  gemm_bt<2,float,short><<<dim3(16,64),256,0,stream>>>(hbf, w1T, b1, nullptr, f1, NT_, 2048, 512);

  // out = x1 + f1@W2 + b2  (in-place residual read from out0 is per-element safe)
  gemm_bt64<1,float,float><<<dim3(8,64),256,0,stream>>>(f1, w2T, b2, out0, out0, NT_, 512, 2048);
}

// Round 13
// 554.746 us; speedup vs baseline: 1.3842x; 1.0098x over previous
//
#include <hip/hip_runtime.h>
#include <hip/hip_bf16.h>

#define B_ 2
#define S_ 4096
#define D_ 512
#define H_ 8
#define HD_ 64
#define FF_ 2048
#define NT_ (B_*S_)
#define EPS_ 1e-5f

typedef __attribute__((ext_vector_type(8))) short bf16x8;
typedef __attribute__((ext_vector_type(4))) float f32x4;
typedef __attribute__((ext_vector_type(4))) unsigned int u32x4;

__device__ __forceinline__ short f2bf(float f){
  __hip_bfloat16 h = __float2bfloat16(f);
  return __builtin_bit_cast(short, h);
}
__device__ __forceinline__ float bf2f(short s){
  return __bfloat162float(__builtin_bit_cast(__hip_bfloat16, s));
}
__device__ __forceinline__ unsigned pack2(float lo, float hi){
  return ((unsigned)(unsigned short)f2bf(hi) << 16) | (unsigned short)f2bf(lo);
}
__device__ __forceinline__ void load8(const float* p, float* f){
  f32x4 a = *(const f32x4*)p; f32x4 b = *(const f32x4*)(p+4);
  #pragma unroll
  for (int j=0;j<4;j++){ f[j]=a[j]; f[4+j]=b[j]; }
}
__device__ __forceinline__ void load8(const short* p, float* f){
  bf16x8 v = *(const bf16x8*)p;
  #pragma unroll
  for (int j=0;j<8;j++) f[j]=bf2f(v[j]);
}
__device__ __forceinline__ float ldval(const float* p, size_t i){ return p[i]; }
__device__ __forceinline__ float ldval(const short* p, size_t i){ return bf2f(p[i]); }
__device__ __forceinline__ void stval(float* p, size_t i, float v){ p[i]=v; }
__device__ __forceinline__ void stval(short* p, size_t i, float v){ p[i]=f2bf(v); }

#define GLL(src, dst) __builtin_amdgcn_global_load_lds( \
    (const __attribute__((address_space(1))) void*)(src), \
    (__attribute__((address_space(3))) void*)(dst), 16, 0, 0)

// ------------- transpose: W (KxN fp32) -> WT (NxK bf16) -------------
__global__ __launch_bounds__(256) void transpose_bf(const float* __restrict__ W,
                                                    short* __restrict__ WT, int K, int N){
  __shared__ float tile[32][33];
  int n0 = blockIdx.x*32, k0 = blockIdx.y*32;
  int tx = threadIdx.x, ty = threadIdx.y; // 32 x 8
  #pragma unroll
  for (int i=0;i<32;i+=8)
    tile[ty+i][tx] = W[(size_t)(k0+ty+i)*N + n0+tx];
  __syncthreads();
  #pragma unroll
  for (int i=0;i<32;i+=8)
    WT[(size_t)(n0+ty+i)*K + k0+tx] = f2bf(tile[tx][ty+i]);
}

// ------- transpose V: (B,S,H,HD) bf16 -> VT (B*H, HD, S) bf16 -------
__global__ __launch_bounds__(256) void transpose_v(const short* __restrict__ V,
                                                   short* __restrict__ VT){
  __shared__ short tile[32][33];
  int d0 = blockIdx.x*32, s0 = blockIdx.y*32, bh = blockIdx.z;
  int b = bh >> 3, h = bh & (H_-1);
  const short* Vp = V + (size_t)b*S_*D_ + (size_t)h*HD_;
  short* VTp = VT + (size_t)bh*HD_*S_;
  int tx = threadIdx.x, ty = threadIdx.y;
  #pragma unroll
  for (int i=0;i<32;i+=8)
    tile[ty+i][tx] = Vp[(size_t)(s0+ty+i)*D_ + d0+tx];   // tile[s][d]
  __syncthreads();
  #pragma unroll
  for (int i=0;i<32;i+=8)
    VTp[(size_t)(d0+ty+i)*S_ + s0+tx] = tile[tx][ty+i];
}

// ---------- LayerNorm over D=512, one wave per token, out bf16 ----------
template<typename TIn>
__global__ __launch_bounds__(256) void ln_kernel(const TIn* __restrict__ X,
                                                 const float* __restrict__ G,
                                                 const float* __restrict__ Bt,
                                                 short* __restrict__ O){
  int wid = threadIdx.x>>6, lane = threadIdx.x&63;
  int tok = blockIdx.x*4 + wid;
  const TIn* xp = X + (size_t)tok*D_;
  float f[8]; load8(xp + lane*8, f);
  float s=0.f, s2=0.f;
  #pragma unroll
  for (int j=0;j<8;j++){ s+=f[j]; s2+=f[j]*f[j]; }
  #pragma unroll
  for (int m=1;m<64;m<<=1){ s += __shfl_xor(s,m); s2 += __shfl_xor(s2,m); }
  float mu = s*(1.f/D_);
  float var = s2*(1.f/D_) - mu*mu;
  float rr = rsqrtf(var + EPS_);
  f32x4 g0 = *(const f32x4*)(G + lane*8), g1v = *(const f32x4*)(G + lane*8 + 4);
  f32x4 b0 = *(const f32x4*)(Bt + lane*8), b1v = *(const f32x4*)(Bt + lane*8 + 4);
  bf16x8 o;
  #pragma unroll
  for (int j=0;j<4;j++){
    o[j]   = f2bf((f[j]-mu)*rr*g0[j]  + b0[j]);
    o[4+j] = f2bf((f[4+j]-mu)*rr*g1v[j] + b1v[j]);
  }
  *(bf16x8*)(O + (size_t)tok*D_ + lane*8) = o;
}

// ---- GEMM 128x128: C = A(MxK,bf16) * BT(NxK,bf16)^T + bias(fp32), epilogue ----
// EPI: 0 = bias only; 1 = bias + residual; 2 = bias + exact GELU
template<int EPI, typename TR, typename TO>
__global__ __launch_bounds__(256) void gemm_bt(const short* __restrict__ A,
                                               const short* __restrict__ BT,
                                               const float* __restrict__ bias,
                                               const TR* __restrict__ res,
                                               TO* __restrict__ out,
                                               int M, int N, int K){
  __shared__ short As[128][40];
  __shared__ short Bs[128][40];
  int m0 = blockIdx.y*128, n0 = blockIdx.x*128;
  int tid = threadIdx.x, lane = tid&63, wid = tid>>6;
  int wr = wid>>1, wc = wid&1;
  int r = lane&15, kk = (lane>>4)*8;
  int arow = tid>>2, acol = (tid&3)*8;
  f32x4 zero = {0.f,0.f,0.f,0.f};
  f32x4 acc[4][4];
  #pragma unroll
  for (int i=0;i<4;i++)
    #pragma unroll
    for (int j=0;j<4;j++) acc[i][j] = zero;

  for (int k0=0;k0<K;k0+=32){
    __syncthreads();
    *(bf16x8*)&As[arow][acol]    = *(const bf16x8*)&A [(size_t)(m0+arow)*K    + k0+acol];
    *(bf16x8*)&As[arow+64][acol] = *(const bf16x8*)&A [(size_t)(m0+arow+64)*K + k0+acol];
    *(bf16x8*)&Bs[arow][acol]    = *(const bf16x8*)&BT[(size_t)(n0+arow)*K    + k0+acol];
    *(bf16x8*)&Bs[arow+64][acol] = *(const bf16x8*)&BT[(size_t)(n0+arow+64)*K + k0+acol];
    __syncthreads();
    bf16x8 a[4], b[4];
    #pragma unroll
    for (int i=0;i<4;i++) a[i] = *(const bf16x8*)&As[wr*64+i*16+r][kk];
    #pragma unroll
    for (int i=0;i<4;i++) b[i] = *(const bf16x8*)&Bs[wc*64+i*16+r][kk];
    #pragma unroll
    for (int mi=0;mi<4;mi++)
      #pragma unroll
      for (int ni=0;ni<4;ni++)
        acc[mi][ni] = __builtin_amdgcn_mfma_f32_16x16x32_bf16(a[mi], b[ni], acc[mi][ni], 0,0,0);
  }
  #pragma unroll
  for (int mi=0;mi<4;mi++){
    #pragma unroll
    for (int ni=0;ni<4;ni++){
      int col = n0 + wc*64 + ni*16 + r;
      float bs = bias[col];
      #pragma unroll
      for (int j=0;j<4;j++){
        int row = m0 + wr*64 + mi*16 + (lane>>4)*4 + j;
        float v = acc[mi][ni][j] + bs;
        if (EPI==1) v += ldval(res, (size_t)row*N + col);
        if (EPI==2) v = 0.5f*v*(1.f + erff(v*0.70710678118f));
        stval(out, (size_t)row*N + col, v);
      }
    }
  }
}

// ---- GEMM 128x64 tile: for N=512-class GEMMs (grid 512 blocks -> 2+/CU) ----
template<int EPI, typename TR, typename TO>
__global__ __launch_bounds__(256) void gemm_bt64(const short* __restrict__ A,
                                                 const short* __restrict__ BT,
                                                 const float* __restrict__ bias,
                                                 const TR* __restrict__ res,
                                                 TO* __restrict__ out,
                                                 int M, int N, int K){
  __shared__ short As[128][40];
  __shared__ short Bs[64][40];
  int m0 = blockIdx.y*128, n0 = blockIdx.x*64;
  int tid = threadIdx.x, lane = tid&63, wid = tid>>6;
  int wr = wid>>1, wc = wid&1;
  int r = lane&15, kk = (lane>>4)*8;
  int arow = tid>>2, acol = (tid&3)*8;
  f32x4 zero = {0.f,0.f,0.f,0.f};
  f32x4 acc[4][2];
  #pragma unroll
  for (int i=0;i<4;i++){ acc[i][0] = zero; acc[i][1] = zero; }

  for (int k0=0;k0<K;k0+=32){
    __syncthreads();
    *(bf16x8*)&As[arow][acol]    = *(const bf16x8*)&A [(size_t)(m0+arow)*K    + k0+acol];
    *(bf16x8*)&As[arow+64][acol] = *(const bf16x8*)&A [(size_t)(m0+arow+64)*K + k0+acol];
    *(bf16x8*)&Bs[arow][acol]    = *(const bf16x8*)&BT[(size_t)(n0+arow)*K    + k0+acol];
    __syncthreads();
    bf16x8 a[4], b[2];
    #pragma unroll
    for (int i=0;i<4;i++) a[i] = *(const bf16x8*)&As[wr*64+i*16+r][kk];
    #pragma unroll
    for (int j=0;j<2;j++) b[j] = *(const bf16x8*)&Bs[wc*32+j*16+r][kk];
    #pragma unroll
    for (int mi=0;mi<4;mi++)
      #pragma unroll
      for (int nj=0;nj<2;nj++)
        acc[mi][nj] = __builtin_amdgcn_mfma_f32_16x16x32_bf16(a[mi], b[nj], acc[mi][nj], 0,0,0);
  }
  #pragma unroll
  for (int mi=0;mi<4;mi++){
    #pragma unroll
    for (int nj=0;nj<2;nj++){
      int col = n0 + wc*32 + nj*16 + r;
      float bs = bias[col];
      #pragma unroll
      for (int j=0;j<4;j++){
        int row = m0 + wr*64 + mi*16 + (lane>>4)*4 + j;
        float v = acc[mi][nj][j] + bs;
        if (EPI==1) v += ldval(res, (size_t)row*N + col);
        if (EPI==2) v = 0.5f*v*(1.f + erff(v*0.70710678118f));
        stval(out, (size_t)row*N + col, v);
      }
    }
  }
}

// -------- attention: block = 64 q-rows of one (b,h); 4 waves with INTERLEAVED
// column schedule (wave w: sc = w*32 + n*128) so the block's 4 waves write
// adjacent 128B chunks per q-row -> one sequential ~512B-append stream per row
// (DRAM-page friendly) instead of 4 disjoint streams. Rest = R8/R12-proven:
// swapped-operand QK^T, global_load_lds + counted vmcnt, XOR-swizzled LDS.
__global__ __launch_bounds__(256, 2) void attn_kernel(const short* __restrict__ Q,
                                                      const short* __restrict__ Kt,
                                                      const short* __restrict__ VT,
                                                      float* __restrict__ attn_o,
                                                      short* __restrict__ ctx){
  __shared__ __align__(16) char smem[65536];   // 4 waves x 16KB staging; combine aliases
  __shared__ float dcomb[4][4][16];
  int wid = threadIdx.x>>6, lane = threadIdx.x&63;
  int bh = blockIdx.y, b = bh>>3, h = bh&7;
  int q0 = blockIdx.x*64;
  int r = lane&15, qh = lane>>4;
  bool hi4 = (lane>>4)&1, hi5 = (lane>>5)&1;
  const short* Qp = Q  + (size_t)b*S_*D_ + (size_t)h*HD_;
  const short* Kp = Kt + (size_t)b*S_*D_ + (size_t)h*HD_;
  const short* Vp = VT + (size_t)bh*HD_*S_;
  float* Ap = attn_o + (size_t)bh*S_*S_;

  char* stg = smem + wid*16384;
  short* KB0 = (short*)stg;         short* KB1 = (short*)(stg+4096);
  short* VB0 = (short*)(stg+8192);  short* VB1 = (short*)(stg+12288);

  // interleaved column schedule: body n covers cols [wid*32 + n*128, +32)
  #define SCOF(n) (wid*32 + (n)*128)

  auto stageK = [&](int sc, short* buf){
    #pragma unroll
    for (int i=0;i<4;i++){
      int row = i*8 + (lane>>3);
      int col = ((lane&7)*8) ^ ((row&7)*8);
      GLL(&Kp[(size_t)(sc+row)*D_ + col], buf + i*512);
    }
  };
  auto stageV = [&](int sc, short* buf){
    #pragma unroll
    for (int i=0;i<4;i++){
      int d = i*16 + (lane>>2);
      int col = ((lane&3)*8) ^ ((d&3)*8);
      GLL(&Vp[(size_t)d*S_ + sc + col], buf + i*512);
    }
  };
  const int kc0 = (qh*16) ^ ((r&7)<<4);
  const int kc1 = (64 + qh*16) ^ ((r&7)<<4);
  const int vc  = (qh*16) ^ ((r&3)<<4);

  bf16x8 aq[4][2];
  #pragma unroll
  for (int qt=0;qt<4;qt++){
    aq[qt][0] = *(const bf16x8*)&Qp[(size_t)(q0+qt*16+r)*D_ + qh*8];
    aq[qt][1] = *(const bf16x8*)&Qp[(size_t)(q0+qt*16+r)*D_ + 32 + qh*8];
  }
  const f32x4 zero = {0.f,0.f,0.f,0.f};

  // ================= sweep 1: denominator =================
  float part[4] = {0.f,0.f,0.f,0.f};

#define S1BODY(n, NW, DOSTG) { \
  asm volatile("s_waitcnt vmcnt(" #NW ")" ::: "memory"); \
  short* kb_ = ((n)&1)? KB1 : KB0; \
  bf16x8 kf0 = *(const bf16x8*)((char*)kb_ + r*128 + kc0); \
  bf16x8 kf1 = *(const bf16x8*)((char*)kb_ + r*128 + kc1); \
  bf16x8 kf2 = *(const bf16x8*)((char*)kb_ + (16+r)*128 + kc0); \
  bf16x8 kf3 = *(const bf16x8*)((char*)kb_ + (16+r)*128 + kc1); \
  asm volatile("s_waitcnt lgkmcnt(0)" ::: "memory"); \
  if (DOSTG) stageK(SCOF((n)+2), kb_); \
  _Pragma("unroll") \
  for (int qt=0;qt<4;qt++){ \
    f32x4 s0 = __builtin_amdgcn_mfma_f32_16x16x32_bf16(kf0, aq[qt][0], zero, 0,0,0); \
    s0 = __builtin_amdgcn_mfma_f32_16x16x32_bf16(kf1, aq[qt][1], s0, 0,0,0); \
    f32x4 s1 = __builtin_amdgcn_mfma_f32_16x16x32_bf16(kf2, aq[qt][0], zero, 0,0,0); \
    s1 = __builtin_amdgcn_mfma_f32_16x16x32_bf16(kf3, aq[qt][1], s1, 0,0,0); \
    _Pragma("unroll") \
    for (int j=0;j<4;j++) part[qt] += __expf(s0[j]*0.125f) + __expf(s1[j]*0.125f); \
  } \
}

  stageK(SCOF(0), KB0); stageK(SCOF(1), KB1);
  S1BODY(0,4,1)
  for (int k2=0;k2<14;k2++){ S1BODY(2*k2+1,4,1) S1BODY(2*k2+2,4,1) }
  S1BODY(29,4,1) S1BODY(30,4,0) S1BODY(31,0,0)
#undef S1BODY

  #pragma unroll
  for (int qt=0;qt<4;qt++){
    part[qt] += __shfl_xor(part[qt],16);
    part[qt] += __shfl_xor(part[qt],32);
  }
  if (lane < 16){
    #pragma unroll
    for (int qt=0;qt<4;qt++) dcomb[wid][qt][r] = part[qt];
  }
  __syncthreads();
  float invl[4];
  #pragma unroll
  for (int qt=0;qt<4;qt++)
    invl[qt] = 1.f/(dcomb[0][qt][r]+dcomb[1][qt][r]+dcomb[2][qt][r]+dcomb[3][qt][r]);

  // ================= sweep 2: attn store + PV =================
  f32x4 cacc[4][4];
  #pragma unroll
  for (int qt=0;qt<4;qt++)
    #pragma unroll
    for (int n2=0;n2<4;n2++) cacc[qt][n2] = zero;

#define S2BODY(n, NW, DOSTG) { \
  asm volatile("s_waitcnt vmcnt(" #NW ")" ::: "memory"); \
  short* kb_ = ((n)&1)? KB1 : KB0; \
  short* vb_ = ((n)&1)? VB1 : VB0; \
  int sc_ = SCOF(n); \
  bf16x8 kf0 = *(const bf16x8*)((char*)kb_ + r*128 + kc0); \
  bf16x8 kf1 = *(const bf16x8*)((char*)kb_ + r*128 + kc1); \
  bf16x8 kf2 = *(const bf16x8*)((char*)kb_ + (16+r)*128 + kc0); \
  bf16x8 kf3 = *(const bf16x8*)((char*)kb_ + (16+r)*128 + kc1); \
  bf16x8 vf0 = *(const bf16x8*)((char*)vb_ + (r)*64    + vc); \
  bf16x8 vf1 = *(const bf16x8*)((char*)vb_ + (16+r)*64 + vc); \
  bf16x8 vf2 = *(const bf16x8*)((char*)vb_ + (32+r)*64 + vc); \
  bf16x8 vf3 = *(const bf16x8*)((char*)vb_ + (48+r)*64 + vc); \
  asm volatile("s_waitcnt lgkmcnt(0)" ::: "memory"); \
  if (DOSTG){ stageK(SCOF((n)+2), kb_); stageV(SCOF((n)+2), vb_); } \
  _Pragma("unroll") \
  for (int qt=0;qt<4;qt++){ \
    f32x4 s0 = __builtin_amdgcn_mfma_f32_16x16x32_bf16(kf0, aq[qt][0], zero, 0,0,0); \
    s0 = __builtin_amdgcn_mfma_f32_16x16x32_bf16(kf1, aq[qt][1], s0, 0,0,0); \
    f32x4 s1 = __builtin_amdgcn_mfma_f32_16x16x32_bf16(kf2, aq[qt][0], zero, 0,0,0); \
    s1 = __builtin_amdgcn_mfma_f32_16x16x32_bf16(kf3, aq[qt][1], s1, 0,0,0); \
    float e0[4], e1[4]; \
    _Pragma("unroll") \
    for (int j=0;j<4;j++){ \
      e0[j] = __expf(s0[j]*0.125f)*invl[qt]; \
      e1[j] = __expf(s1[j]*0.125f)*invl[qt]; \
    } \
    f32x4 o0 = {e0[0],e0[1],e0[2],e0[3]}; \
    f32x4 o1 = {e1[0],e1[1],e1[2],e1[3]}; \
    float* dst = &Ap[(size_t)(q0+qt*16+r)*S_ + sc_ + qh*4]; \
    *(f32x4*)dst = o0; \
    *(f32x4*)(dst+16) = o1; \
    unsigned v0 = pack2(e0[0],e0[1]), v1 = pack2(e0[2],e0[3]); \
    unsigned v2 = pack2(e1[0],e1[1]), v3 = pack2(e1[2],e1[3]); \
    unsigned u0 = __shfl_xor((int)v0,16), u1 = __shfl_xor((int)v1,16); \
    unsigned u2 = __shfl_xor((int)v2,16), u3 = __shfl_xor((int)v3,16); \
    unsigned s0c0 = hi4?u0:v0, s0c1 = hi4?u1:v1, s0c2 = hi4?v0:u0, s0c3 = hi4?v1:u1; \
    unsigned s1c0 = hi4?u2:v2, s1c1 = hi4?u3:v3, s1c2 = hi4?v2:u2, s1c3 = hi4?v3:u3; \
    unsigned w0 = hi5?s0c0:s1c0, w1 = hi5?s0c1:s1c1, w2 = hi5?s0c2:s1c2, w3 = hi5?s0c3:s1c3; \
    unsigned wp0 = __shfl_xor((int)w0,32), wp1 = __shfl_xor((int)w1,32); \
    unsigned wp2 = __shfl_xor((int)w2,32), wp3 = __shfl_xor((int)w3,32); \
    u32x4 pw; \
    pw[0] = (qh==0)?s0c0:(qh==3)?s1c0:wp0; \
    pw[1] = (qh==0)?s0c1:(qh==3)?s1c1:wp1; \
    pw[2] = (qh==0)?s0c2:(qh==3)?s1c2:wp2; \
    pw[3] = (qh==0)?s0c3:(qh==3)?s1c3:wp3; \
    bf16x8 pa = __builtin_bit_cast(bf16x8, pw); \
    cacc[qt][0] = __builtin_amdgcn_mfma_f32_16x16x32_bf16(pa, vf0, cacc[qt][0], 0,0,0); \
    cacc[qt][1] = __builtin_amdgcn_mfma_f32_16x16x32_bf16(pa, vf1, cacc[qt][1], 0,0,0); \
    cacc[qt][2] = __builtin_amdgcn_mfma_f32_16x16x32_bf16(pa, vf2, cacc[qt][2], 0,0,0); \
    cacc[qt][3] = __builtin_amdgcn_mfma_f32_16x16x32_bf16(pa, vf3, cacc[qt][3], 0,0,0); \
  } \
}

  stageK(SCOF(0), KB0); stageV(SCOF(0), VB0);
  stageK(SCOF(1), KB1); stageV(SCOF(1), VB1);
  S2BODY(0,8,1)
  for (int k2=0;k2<14;k2++){ S2BODY(2*k2+1,16,1) S2BODY(2*k2+2,16,1) }
  S2BODY(29,16,1) S2BODY(30,16,0) S2BODY(31,8,0)
#undef S2BODY
#undef SCOF

  // ---------------- 4-way PV combine, write ctx ----------------
  __syncthreads();
  float* cmb = (float*)smem;
  if (wid & 1){
    float* dstp = cmb + (wid>>1)*4096;
    #pragma unroll
    for (int qt=0;qt<4;qt++)
      #pragma unroll
      for (int n2=0;n2<4;n2++)
        #pragma unroll
        for (int j=0;j<4;j++)
          dstp[(qt*16+qh*4+j)*64 + n2*16 + r] = cacc[qt][n2][j];
  }
  __syncthreads();
  if (!(wid & 1)){
    float* srcp = cmb + (wid>>1)*4096;
    #pragma unroll
    for (int qt=0;qt<4;qt++)
      #pragma unroll
      for (int n2=0;n2<4;n2++)
        #pragma unroll
        for (int j=0;j<4;j++)
          cacc[qt][n2][j] += srcp[(qt*16+qh*4+j)*64 + n2*16 + r];
  }
  __syncthreads();
  if (wid == 2){
    #pragma unroll
    for (int qt=0;qt<4;qt++)
      #pragma unroll
      for (int n2=0;n2<4;n2++)
        #pragma unroll
        for (int j=0;j<4;j++)
          cmb[(qt*16+qh*4+j)*64 + n2*16 + r] = cacc[qt][n2][j];
  }
  __syncthreads();
  if (wid == 0){
    #pragma unroll
    for (int qt=0;qt<4;qt++)
      #pragma unroll
      for (int n2=0;n2<4;n2++)
        #pragma unroll
        for (int j=0;j<4;j++){
          float v = cacc[qt][n2][j] + cmb[(qt*16+qh*4+j)*64 + n2*16 + r];
          ctx[(size_t)(b*S_ + q0 + qt*16 + qh*4 + j)*D_ + h*HD_ + n2*16 + r] = f2bf(v);
        }
  }
}

// --------------------------------- host ---------------------------------
extern "C" void kernel_launch(void* const* d_in, const int* in_sizes, int n_in,
                              void* d_out, int out_size, void* d_ws, size_t ws_size,
                              hipStream_t stream){
  const float* x   = (const float*)d_in[0];
  const float* Wq  = (const float*)d_in[1];
  const float* bq  = (const float*)d_in[2];
  const float* Wk  = (const float*)d_in[3];
  const float* bk  = (const float*)d_in[4];
  const float* Wv  = (const float*)d_in[5];
  const float* bv  = (const float*)d_in[6];
  const float* Wo  = (const float*)d_in[7];
  const float* bo  = (const float*)d_in[8];
  const float* W1  = (const float*)d_in[9];
  const float* b1  = (const float*)d_in[10];
  const float* W2  = (const float*)d_in[11];
  const float* b2  = (const float*)d_in[12];
  const float* g1  = (const float*)d_in[13];
  const float* be1 = (const float*)d_in[14];
  const float* g2  = (const float*)d_in[15];
  const float* be2 = (const float*)d_in[16];

  char* ws = (char*)d_ws;
  const size_t KB = 1024;
  short* wqT = (short*)(ws + 0*KB);
  short* wkT = (short*)(ws + 512*KB);
  short* wvT = (short*)(ws + 1024*KB);
  short* woT = (short*)(ws + 1536*KB);
  short* w1T = (short*)(ws + 2048*KB);    // 2 MB
  short* w2T = (short*)(ws + 4096*KB);    // 2 MB
  short* hbf = (short*)(ws + 6144*KB);    // 8 MB  (LN1 out; reused for LN2 out)
  short* Qb  = (short*)(ws + 14336*KB);   // 8 MB
  short* Kb  = (short*)(ws + 22528*KB);   // 8 MB
  short* Vb  = (short*)(ws + 30720*KB);   // 8 MB
  short* VTb = (short*)(ws + 38912*KB);   // 8 MB
  short* ctx = (short*)(ws + 47104*KB);   // 8 MB
  short* f1  = (short*)(ws + 14336*KB);   // 32 MB, aliases Q/K/V/VT (dead after attn)

  float* out0 = (float*)d_out;                      // [8192,512] fp32; also holds x1
  float* attn = out0 + (size_t)NT_*D_;              // [16,4096,4096] fp32

  dim3 tb(32,8);
  transpose_bf<<<dim3(16,16),tb,0,stream>>>(Wq, wqT, 512, 512);
  transpose_bf<<<dim3(16,16),tb,0,stream>>>(Wk, wkT, 512, 512);
  transpose_bf<<<dim3(16,16),tb,0,stream>>>(Wv, wvT, 512, 512);
  transpose_bf<<<dim3(16,16),tb,0,stream>>>(Wo, woT, 512, 512);
  transpose_bf<<<dim3(64,16),tb,0,stream>>>(W1, w1T, 512, 2048);
  transpose_bf<<<dim3(16,64),tb,0,stream>>>(W2, w2T, 2048, 512);

  ln_kernel<float><<<NT_/4, 256, 0, stream>>>(x, g1, be1, hbf);

  gemm_bt64<0,float,short><<<dim3(8,64),256,0,stream>>>(hbf, wqT, bq, nullptr, Qb, NT_, 512, 512);
  gemm_bt64<0,float,short><<<dim3(8,64),256,0,stream>>>(hbf, wkT, bk, nullptr, Kb, NT_, 512, 512);
  gemm_bt64<0,float,short><<<dim3(8,64),256,0,stream>>>(hbf, wvT, bv, nullptr, Vb, NT_, 512, 512);

  transpose_v<<<dim3(2,128,16),tb,0,stream>>>(Vb, VTb);

  attn_kernel<<<dim3(64,16), 256, 0, stream>>>(Qb, Kb, VTb, attn, ctx);

  // x1 = x + ctx@Wo + bo   -> stored fp32 in out0
  gemm_bt64<1,float,float><<<dim3(8,64),256,0,stream>>>(ctx, woT, bo, x, out0, NT_, 512, 512);

  ln_kernel<float><<<NT_/4, 256, 0, stream>>>(out0, g2, be2, hbf);

  gemm_bt<2,float,short><<<dim3(16,64),256,0,stream>>>(hbf, w1T, b1, nullptr, f1, NT_, 2048, 512);

  // out = x1 + f1@W2 + b2  (in-place residual read from out0 is per-element safe)
  gemm_bt64<1,float,float><<<dim3(8,64),256,0,stream>>>(f1, w2T, b2, out0, out0, NT_, 512, 2048);
}